// Round 2
// baseline (44471.207 us; speedup 1.0000x reference)
//
#include <hip/hip_runtime.h>

// Problem constants (match reference)
#define NB 100000
#define NS 50000
#define DD 128
constexpr int E_BB = 800000, E_SB = 400000, E_BS = 400000;

// ---------------------------------------------------------------------------
// Weight prep: build concatenated GEMM weights
//   Wb_l [384][128] = [Wl[l,0]; Wl[l,1]; Wr[l,0]+Wr[l,1]]
//   Ws0  [256][128] = [Wl[0,2]; Wr[0,2]]
//   biases: bb_l = bl[l,0]+bl[l,1]; bs0 = bl[0,2]
// ---------------------------------------------------------------------------
__global__ void prep_weights(const float* __restrict__ Wl, const float* __restrict__ bl,
                             const float* __restrict__ Wr,
                             float* __restrict__ wb0, float* __restrict__ wb1,
                             float* __restrict__ ws0,
                             float* __restrict__ bb0, float* __restrict__ bb1,
                             float* __restrict__ bs0) {
    int i = blockIdx.x * blockDim.x + threadIdx.x;
    if (i < 384 * 128) {
        int k = i >> 7, n = i & 127;
        #pragma unroll
        for (int l = 0; l < 2; ++l) {
            float v;
            if (k < 128)      v = Wl[((l*3 + 0)*128 + k)*128 + n];
            else if (k < 256) v = Wl[((l*3 + 1)*128 + (k-128))*128 + n];
            else              v = Wr[((l*3 + 0)*128 + (k-256))*128 + n]
                                + Wr[((l*3 + 1)*128 + (k-256))*128 + n];
            (l ? wb1 : wb0)[i] = v;
        }
    }
    if (i < 256 * 128) {
        int k = i >> 7, n = i & 127;
        ws0[i] = (k < 128) ? Wl[((0*3 + 2)*128 + k)*128 + n]
                           : Wr[((0*3 + 2)*128 + (k-128))*128 + n];
    }
    if (i < 128) {
        bb0[i] = bl[(0*3 + 0)*128 + i] + bl[(0*3 + 1)*128 + i];
        bb1[i] = bl[(1*3 + 0)*128 + i] + bl[(1*3 + 1)*128 + i];
        bs0[i] = bl[(0*3 + 2)*128 + i];
    }
}

// ---------------------------------------------------------------------------
// CSR build: histogram -> single-block scan -> atomic-ticket fill
// ---------------------------------------------------------------------------
__global__ void hist_kernel(const int* __restrict__ dst, int E, int* __restrict__ off) {
    int i = blockIdx.x * blockDim.x + threadIdx.x;
    if (i < E) {
        int d = dst[i];
        atomicAdd(&off[d + 1], 1);   // cnt lands at off[d+1]; inclusive scan -> exclusive offsets
    }
}

// single-block inclusive scan in-place over a[0..n1). a[0]==0 so result is exclusive offsets.
__global__ void scan_kernel(int* __restrict__ a, int n1) {
    __shared__ int sums[1024];
    int t = threadIdx.x;
    int chunk = (n1 + 1023) / 1024;
    int s = t * chunk, e = min(s + chunk, n1);
    int sum = 0;
    for (int i = s; i < e; ++i) sum += a[i];
    sums[t] = sum;
    __syncthreads();
    for (int d = 1; d < 1024; d <<= 1) {
        int v = (t >= d) ? sums[t - d] : 0;
        __syncthreads();
        sums[t] += v;
        __syncthreads();
    }
    int base = (t == 0) ? 0 : sums[t - 1];
    for (int i = s; i < e; ++i) { base += a[i]; a[i] = base; }
}

__global__ void fill_kernel(const int* __restrict__ src, const int* __restrict__ dst, int E,
                            const int* __restrict__ off, int* __restrict__ tick,
                            int* __restrict__ csr) {
    int i = blockIdx.x * blockDim.x + threadIdx.x;
    if (i < E) {
        int d = dst[i];
        int pos = off[d] + atomicAdd(&tick[d], 1);
        csr[pos] = src[i];
    }
}

// ---------------------------------------------------------------------------
// Mean aggregation: one 64-lane wave per dst node, float2 per lane (512B/row)
// ---------------------------------------------------------------------------
__global__ __launch_bounds__(256)
void agg_mean(const float* __restrict__ xsrc, const int* __restrict__ off,
              const int* __restrict__ csr, float* __restrict__ out, int n) {
    int node = blockIdx.x * 4 + (threadIdx.x >> 6);
    if (node >= n) return;
    int lane = threadIdx.x & 63;
    int s = off[node], e = off[node + 1];
    float ax = 0.f, ay = 0.f;
    for (int p = s; p < e; ++p) {
        int j = csr[p];
        float2 v = *(const float2*)&xsrc[(size_t)j * DD + lane * 2];
        ax += v.x; ay += v.y;
    }
    float inv = 1.0f / fmaxf((float)(e - s), 1.0f);
    float2 r; r.x = ax * inv; r.y = ay * inv;
    *(float2*)&out[(size_t)node * DD + lane * 2] = r;
}

// ---------------------------------------------------------------------------
// Fused GEMM: out = leakyrelu([A0|A1|A2] @ W + bias), W prepped [KTILES*128][128]
// BM=64, BN=128, BK=32, 256 threads; thread tile 4x8. In-place-safe (block
// reads only its own output rows of A).
// ---------------------------------------------------------------------------
template<int KTILES>
__global__ __launch_bounds__(256)
void gemm_fused(const float* __restrict__ A0, const float* __restrict__ A1,
                const float* __restrict__ A2,
                const float* __restrict__ W, const float* __restrict__ bias,
                float* __restrict__ out, int M) {
    __shared__ float As[32][68];    // transposed A-tile [k][m], padded
    __shared__ float Bs[32][132];   // B-tile [k][n], padded
    const int tid = threadIdx.x;
    const int tx = tid & 15;        // col group: cols tx*8..+8
    const int ty = tid >> 4;        // row group: rows ty*4..+4
    const int rowbase = blockIdx.x * 64;
    float acc[4][8] = {};
    const float* slabs[3] = {A0, A1, A2};

    #pragma unroll
    for (int kt = 0; kt < KTILES * 4; ++kt) {
        const float* A = slabs[kt >> 2];
        const int k0 = (kt & 3) * 32;
        // A-tile: 64 rows x 32 k = 512 float4, 2 per thread, store transposed
        #pragma unroll
        for (int f = 0; f < 2; ++f) {
            int fid = tid + f * 256;
            int r = fid >> 3, kq = fid & 7;
            int row = rowbase + r;
            float4 v = make_float4(0.f, 0.f, 0.f, 0.f);
            if (row < M) v = *(const float4*)&A[(size_t)row * DD + k0 + kq * 4];
            As[kq*4+0][r] = v.x; As[kq*4+1][r] = v.y;
            As[kq*4+2][r] = v.z; As[kq*4+3][r] = v.w;
        }
        // B-tile: 32 k x 128 n = 1024 float4, 4 per thread
        #pragma unroll
        for (int f = 0; f < 4; ++f) {
            int fid = tid + f * 256;
            int kk = fid >> 5, nq = fid & 31;
            *(float4*)&Bs[kk][nq * 4] = *(const float4*)&W[(size_t)(kt * 32 + kk) * 128 + nq * 4];
        }
        __syncthreads();
        #pragma unroll
        for (int k = 0; k < 32; ++k) {
            float4 a  = *(const float4*)&As[k][ty * 4];
            float4 b0 = *(const float4*)&Bs[k][tx * 8];
            float4 b1 = *(const float4*)&Bs[k][tx * 8 + 4];
            float av[4] = {a.x, a.y, a.z, a.w};
            float bv[8] = {b0.x, b0.y, b0.z, b0.w, b1.x, b1.y, b1.z, b1.w};
            #pragma unroll
            for (int i = 0; i < 4; ++i)
                #pragma unroll
                for (int j = 0; j < 8; ++j)
                    acc[i][j] += av[i] * bv[j];
        }
        __syncthreads();
    }
    #pragma unroll
    for (int i = 0; i < 4; ++i) {
        int row = rowbase + ty * 4 + i;
        if (row < M) {
            #pragma unroll
            for (int j = 0; j < 8; ++j) {
                float v = acc[i][j] + bias[tx * 8 + j];
                v = (v > 0.f) ? v : 0.01f * v;
                out[(size_t)row * 128 + tx * 8 + j] = v;
            }
        }
    }
}

// ---------------------------------------------------------------------------
// Head: out[i,h] = sum_c x[i,c]*Wh[h,c] + bh[h]; one wave per row
// ---------------------------------------------------------------------------
__global__ __launch_bounds__(256)
void head_kernel(const float* __restrict__ x, const float* __restrict__ Wh,
                 const float* __restrict__ bh, float* __restrict__ out, int M) {
    __shared__ float w[8][128];
    int tid = threadIdx.x;
    for (int i = tid; i < 1024; i += 256) w[i >> 7][i & 127] = Wh[i];
    __syncthreads();
    int row = blockIdx.x * 4 + (tid >> 6);
    if (row >= M) return;
    int lane = tid & 63;
    float2 v = *(const float2*)&x[(size_t)row * DD + lane * 2];
    float acc[8];
    #pragma unroll
    for (int h = 0; h < 8; ++h)
        acc[h] = v.x * w[h][lane * 2] + v.y * w[h][lane * 2 + 1];
    #pragma unroll
    for (int h = 0; h < 8; ++h) {
        float s = acc[h];
        #pragma unroll
        for (int d = 32; d >= 1; d >>= 1) s += __shfl_xor(s, d);
        acc[h] = s;
    }
    if (lane == 0) {
        #pragma unroll
        for (int h = 0; h < 8; ++h) out[(size_t)row * 8 + h] = acc[h] + bh[h];
    }
}

// ---------------------------------------------------------------------------
extern "C" void kernel_launch(void* const* d_in, const int* in_sizes, int n_in,
                              void* d_out, int out_size, void* d_ws, size_t ws_size,
                              hipStream_t stream) {
    const float* x_b = (const float*)d_in[0];
    const float* x_s = (const float*)d_in[1];
    const float* Wl  = (const float*)d_in[2];
    const float* bl  = (const float*)d_in[3];
    const float* Wr  = (const float*)d_in[4];
    const float* Wh  = (const float*)d_in[5];
    const float* bh  = (const float*)d_in[6];
    const int* ei_bb = (const int*)d_in[7];
    const int* ei_sb = (const int*)d_in[8];
    const int* ei_bs = (const int*)d_in[9];
    float* out = (float*)d_out;

    char* p = (char*)d_ws;
    auto alloc = [&](size_t bytes) { char* r = p; p += (bytes + 255) & ~255ull; return r; };
    int* off_bb = (int*)alloc((NB + 1) * 4);
    int* off_sb = (int*)alloc((NB + 1) * 4);
    int* off_bs = (int*)alloc((NS + 1) * 4);
    int* csr_bb = (int*)alloc((size_t)E_BB * 4);
    int* csr_sb = (int*)alloc((size_t)E_SB * 4);
    int* csr_bs = (int*)alloc((size_t)E_BS * 4);
    int* tick   = (int*)alloc((size_t)NB * 4);
    float* m1  = (float*)alloc((size_t)NB * 128 * 4);
    float* m2  = (float*)alloc((size_t)NB * 128 * 4);
    float* m3  = (float*)alloc((size_t)NS * 128 * 4);
    float* hb  = (float*)alloc((size_t)NB * 128 * 4);
    float* wb0 = (float*)alloc(384 * 128 * 4);
    float* wb1 = (float*)alloc(384 * 128 * 4);
    float* ws0 = (float*)alloc(256 * 128 * 4);
    float* bb0 = (float*)alloc(128 * 4);
    float* bb1 = (float*)alloc(128 * 4);
    float* bs0 = (float*)alloc(128 * 4);

    prep_weights<<<192, 256, 0, stream>>>(Wl, bl, Wr, wb0, wb1, ws0, bb0, bb1, bs0);

    auto build_csr = [&](const int* ei, int E, int n, int* off, int* csr) {
        hipMemsetAsync(off, 0, (size_t)(n + 1) * 4, stream);
        hist_kernel<<<(E + 255) / 256, 256, 0, stream>>>(ei + E, E, off);
        scan_kernel<<<1, 1024, 0, stream>>>(off, n + 1);
        hipMemsetAsync(tick, 0, (size_t)n * 4, stream);
        fill_kernel<<<(E + 255) / 256, 256, 0, stream>>>(ei, ei + E, E, off, tick, csr);
    };
    build_csr(ei_bb, E_BB, NB, off_bb, csr_bb);
    build_csr(ei_sb, E_SB, NB, off_sb, csr_sb);
    build_csr(ei_bs, E_BS, NS, off_bs, csr_bs);

    // ---- layer 0 ----
    agg_mean<<<(NB + 3) / 4, 256, 0, stream>>>(x_b, off_bb, csr_bb, m1, NB);
    agg_mean<<<(NB + 3) / 4, 256, 0, stream>>>(x_s, off_sb, csr_sb, m2, NB);
    agg_mean<<<(NS + 3) / 4, 256, 0, stream>>>(x_b, off_bs, csr_bs, m3, NS);
    gemm_fused<3><<<(NB + 63) / 64, 256, 0, stream>>>(m1, m2, x_b, wb0, bb0, hb, NB);
    gemm_fused<2><<<(NS + 63) / 64, 256, 0, stream>>>(m3, x_s, nullptr, ws0, bs0, m3, NS); // in-place -> h_s

    // ---- layer 1 (seller update is dead code: output only needs x_b) ----
    agg_mean<<<(NB + 3) / 4, 256, 0, stream>>>(hb, off_bb, csr_bb, m1, NB);
    agg_mean<<<(NB + 3) / 4, 256, 0, stream>>>(m3, off_sb, csr_sb, m2, NB);
    gemm_fused<3><<<(NB + 63) / 64, 256, 0, stream>>>(m1, m2, hb, wb1, bb1, m1, NB); // in-place

    // ---- heads ----
    head_kernel<<<(NB + 3) / 4, 256, 0, stream>>>(m1, Wh, bh, out, NB);
}

// Round 4
// 1431.157 us; speedup vs baseline: 31.0736x; 31.0736x over previous
//
#include <hip/hip_runtime.h>

// Problem constants (match reference)
#define NB 100000
#define NS 50000
#define DD 128
constexpr int E_BB = 800000, E_SB = 400000, E_BS = 400000;

// ---------------------------------------------------------------------------
// Weight prep: build concatenated GEMM weights
//   Wb_l [384][128] = [Wl[l,0]; Wl[l,1]; Wr[l,0]+Wr[l,1]]
//   Ws0  [256][128] = [Wl[0,2]; Wr[0,2]]
//   biases: bb_l = bl[l,0]+bl[l,1]; bs0 = bl[0,2]
// ---------------------------------------------------------------------------
__global__ void prep_weights(const float* __restrict__ Wl, const float* __restrict__ bl,
                             const float* __restrict__ Wr,
                             float* __restrict__ wb0, float* __restrict__ wb1,
                             float* __restrict__ ws0,
                             float* __restrict__ bb0, float* __restrict__ bb1,
                             float* __restrict__ bs0) {
    int i = blockIdx.x * blockDim.x + threadIdx.x;
    if (i < 384 * 128) {
        int k = i >> 7, n = i & 127;
        #pragma unroll
        for (int l = 0; l < 2; ++l) {
            float v;
            if (k < 128)      v = Wl[((l*3 + 0)*128 + k)*128 + n];
            else if (k < 256) v = Wl[((l*3 + 1)*128 + (k-128))*128 + n];
            else              v = Wr[((l*3 + 0)*128 + (k-256))*128 + n]
                                + Wr[((l*3 + 1)*128 + (k-256))*128 + n];
            (l ? wb1 : wb0)[i] = v;
        }
    }
    if (i < 256 * 128) {
        int k = i >> 7, n = i & 127;
        ws0[i] = (k < 128) ? Wl[((0*3 + 2)*128 + k)*128 + n]
                           : Wr[((0*3 + 2)*128 + (k-128))*128 + n];
    }
    if (i < 128) {
        bb0[i] = bl[(0*3 + 0)*128 + i] + bl[(0*3 + 1)*128 + i];
        bb1[i] = bl[(1*3 + 0)*128 + i] + bl[(1*3 + 1)*128 + i];
        bs0[i] = bl[(0*3 + 2)*128 + i];
    }
}

// ---------------------------------------------------------------------------
// CSR build: histogram -> single-block scan -> atomic-ticket fill
// ---------------------------------------------------------------------------
__global__ void hist_kernel(const int* __restrict__ dst, int E, int* __restrict__ off) {
    int i = blockIdx.x * blockDim.x + threadIdx.x;
    if (i < E) {
        int d = dst[i];
        atomicAdd(&off[d + 1], 1);   // cnt lands at off[d+1]; inclusive scan -> exclusive offsets
    }
}

// single-block inclusive scan in-place over a[0..n1). a[0]==0 so result is exclusive offsets.
__global__ void scan_kernel(int* __restrict__ a, int n1) {
    __shared__ int sums[1024];
    int t = threadIdx.x;
    int chunk = (n1 + 1023) / 1024;
    int s = t * chunk, e = min(s + chunk, n1);
    int sum = 0;
    for (int i = s; i < e; ++i) sum += a[i];
    sums[t] = sum;
    __syncthreads();
    for (int d = 1; d < 1024; d <<= 1) {
        int v = (t >= d) ? sums[t - d] : 0;
        __syncthreads();
        sums[t] += v;
        __syncthreads();
    }
    int base = (t == 0) ? 0 : sums[t - 1];
    for (int i = s; i < e; ++i) { base += a[i]; a[i] = base; }
}

__global__ void fill_kernel(const int* __restrict__ src, const int* __restrict__ dst, int E,
                            const int* __restrict__ off, int* __restrict__ tick,
                            int* __restrict__ csr) {
    int i = blockIdx.x * blockDim.x + threadIdx.x;
    if (i < E) {
        int d = dst[i];
        int pos = off[d] + atomicAdd(&tick[d], 1);
        csr[pos] = src[i];
    }
}

// ---------------------------------------------------------------------------
// Mean aggregation: one 64-lane wave per dst node, float2 per lane (512B/row)
// ---------------------------------------------------------------------------
__global__ __launch_bounds__(256)
void agg_mean(const float* __restrict__ xsrc, const int* __restrict__ off,
              const int* __restrict__ csr, float* __restrict__ out, int n) {
    int node = blockIdx.x * 4 + (threadIdx.x >> 6);
    if (node >= n) return;
    int lane = threadIdx.x & 63;
    int s = off[node], e = off[node + 1];
    float ax = 0.f, ay = 0.f;
    for (int p = s; p < e; ++p) {
        int j = csr[p];
        float2 v = *(const float2*)&xsrc[(size_t)j * DD + lane * 2];
        ax += v.x; ay += v.y;
    }
    float inv = 1.0f / fmaxf((float)(e - s), 1.0f);
    float2 r; r.x = ax * inv; r.y = ay * inv;
    *(float2*)&out[(size_t)node * DD + lane * 2] = r;
}

// ---------------------------------------------------------------------------
// Fused GEMM: out = leakyrelu([A0|A1|A2] @ W + bias), W prepped [KTILES*128][128]
// BM=64, BN=128, BK=32, 256 threads; thread tile 4x8.
// R2 spill fix: VGPR_Count was 256 with ~70x HBM over-fetch (acc spilled to
// scratch; full kt-unroll stretched live ranges). Now: unroll 1 on tile loops,
// __launch_bounds__(256,4) caps VGPR at 128 (need ~100), unroll 8 inner.
// In-place-safe (block reads only its own output rows of A).
// ---------------------------------------------------------------------------
template<int KTILES>
__global__ __launch_bounds__(256, 4)
void gemm_fused(const float* __restrict__ A0, const float* __restrict__ A1,
                const float* __restrict__ A2,
                const float* __restrict__ W, const float* __restrict__ bias,
                float* __restrict__ out, int M) {
    __shared__ float As[32][68];    // transposed A-tile [k][m], padded
    __shared__ float Bs[32][132];   // B-tile [k][n], padded
    const int tid = threadIdx.x;
    const int tx = tid & 15;        // col group: cols tx*8..+8
    const int ty = tid >> 4;        // row group: rows ty*4..+4
    const int rowbase = blockIdx.x * 64;
    float acc[4][8] = {};

    #pragma unroll 1
    for (int s = 0; s < KTILES; ++s) {
        const float* A = (s == 0) ? A0 : (s == 1) ? A1 : A2;   // uniform scalar select
        #pragma unroll 1
        for (int q = 0; q < 4; ++q) {
            const int k0 = q * 32;
            const int ktile = s * 4 + q;
            // A-tile: 64 rows x 32 k = 512 float4, 2 per thread, store transposed
            #pragma unroll
            for (int f = 0; f < 2; ++f) {
                int fid = tid + f * 256;
                int r = fid >> 3, kq = fid & 7;
                int row = rowbase + r;
                float4 v = make_float4(0.f, 0.f, 0.f, 0.f);
                if (row < M) v = *(const float4*)&A[(size_t)row * DD + k0 + kq * 4];
                As[kq*4+0][r] = v.x; As[kq*4+1][r] = v.y;
                As[kq*4+2][r] = v.z; As[kq*4+3][r] = v.w;
            }
            // B-tile: 32 k x 128 n = 1024 float4, 4 per thread
            #pragma unroll
            for (int f = 0; f < 4; ++f) {
                int fid = tid + f * 256;
                int kk = fid >> 5, nq = fid & 31;
                *(float4*)&Bs[kk][nq * 4] = *(const float4*)&W[(size_t)(ktile * 32 + kk) * 128 + nq * 4];
            }
            __syncthreads();
            #pragma unroll 8
            for (int k = 0; k < 32; ++k) {
                float4 a  = *(const float4*)&As[k][ty * 4];
                float4 b0 = *(const float4*)&Bs[k][tx * 8];
                float4 b1 = *(const float4*)&Bs[k][tx * 8 + 4];
                float av[4] = {a.x, a.y, a.z, a.w};
                float bv[8] = {b0.x, b0.y, b0.z, b0.w, b1.x, b1.y, b1.z, b1.w};
                #pragma unroll
                for (int i = 0; i < 4; ++i)
                    #pragma unroll
                    for (int j = 0; j < 8; ++j)
                        acc[i][j] += av[i] * bv[j];
            }
            __syncthreads();
        }
    }
    #pragma unroll
    for (int i = 0; i < 4; ++i) {
        int row = rowbase + ty * 4 + i;
        if (row < M) {
            #pragma unroll
            for (int j = 0; j < 8; ++j) {
                float v = acc[i][j] + bias[tx * 8 + j];
                v = (v > 0.f) ? v : 0.01f * v;
                out[(size_t)row * 128 + tx * 8 + j] = v;
            }
        }
    }
}

// ---------------------------------------------------------------------------
// Head: out[i,h] = sum_c x[i,c]*Wh[h,c] + bh[h]; one wave per row
// ---------------------------------------------------------------------------
__global__ __launch_bounds__(256)
void head_kernel(const float* __restrict__ x, const float* __restrict__ Wh,
                 const float* __restrict__ bh, float* __restrict__ out, int M) {
    __shared__ float w[8][128];
    int tid = threadIdx.x;
    for (int i = tid; i < 1024; i += 256) w[i >> 7][i & 127] = Wh[i];
    __syncthreads();
    int row = blockIdx.x * 4 + (tid >> 6);
    if (row >= M) return;
    int lane = tid & 63;
    float2 v = *(const float2*)&x[(size_t)row * DD + lane * 2];
    float acc[8];
    #pragma unroll
    for (int h = 0; h < 8; ++h)
        acc[h] = v.x * w[h][lane * 2] + v.y * w[h][lane * 2 + 1];
    #pragma unroll
    for (int h = 0; h < 8; ++h) {
        float s = acc[h];
        #pragma unroll
        for (int d = 32; d >= 1; d >>= 1) s += __shfl_xor(s, d);
        acc[h] = s;
    }
    if (lane == 0) {
        #pragma unroll
        for (int h = 0; h < 8; ++h) out[(size_t)row * 8 + h] = acc[h] + bh[h];
    }
}

// ---------------------------------------------------------------------------
extern "C" void kernel_launch(void* const* d_in, const int* in_sizes, int n_in,
                              void* d_out, int out_size, void* d_ws, size_t ws_size,
                              hipStream_t stream) {
    const float* x_b = (const float*)d_in[0];
    const float* x_s = (const float*)d_in[1];
    const float* Wl  = (const float*)d_in[2];
    const float* bl  = (const float*)d_in[3];
    const float* Wr  = (const float*)d_in[4];
    const float* Wh  = (const float*)d_in[5];
    const float* bh  = (const float*)d_in[6];
    const int* ei_bb = (const int*)d_in[7];
    const int* ei_sb = (const int*)d_in[8];
    const int* ei_bs = (const int*)d_in[9];
    float* out = (float*)d_out;

    char* p = (char*)d_ws;
    auto alloc = [&](size_t bytes) { char* r = p; p += (bytes + 255) & ~255ull; return r; };
    int* off_bb = (int*)alloc((NB + 1) * 4);
    int* off_sb = (int*)alloc((NB + 1) * 4);
    int* off_bs = (int*)alloc((NS + 1) * 4);
    int* csr_bb = (int*)alloc((size_t)E_BB * 4);
    int* csr_sb = (int*)alloc((size_t)E_SB * 4);
    int* csr_bs = (int*)alloc((size_t)E_BS * 4);
    int* tick   = (int*)alloc((size_t)NB * 4);
    float* m1  = (float*)alloc((size_t)NB * 128 * 4);
    float* m2  = (float*)alloc((size_t)NB * 128 * 4);
    float* m3  = (float*)alloc((size_t)NS * 128 * 4);
    float* hb  = (float*)alloc((size_t)NB * 128 * 4);
    float* wb0 = (float*)alloc(384 * 128 * 4);
    float* wb1 = (float*)alloc(384 * 128 * 4);
    float* ws0 = (float*)alloc(256 * 128 * 4);
    float* bb0 = (float*)alloc(128 * 4);
    float* bb1 = (float*)alloc(128 * 4);
    float* bs0 = (float*)alloc(128 * 4);

    prep_weights<<<192, 256, 0, stream>>>(Wl, bl, Wr, wb0, wb1, ws0, bb0, bb1, bs0);

    auto build_csr = [&](const int* ei, int E, int n, int* off, int* csr) {
        hipMemsetAsync(off, 0, (size_t)(n + 1) * 4, stream);
        hist_kernel<<<(E + 255) / 256, 256, 0, stream>>>(ei + E, E, off);
        scan_kernel<<<1, 1024, 0, stream>>>(off, n + 1);
        hipMemsetAsync(tick, 0, (size_t)n * 4, stream);
        fill_kernel<<<(E + 255) / 256, 256, 0, stream>>>(ei, ei + E, E, off, tick, csr);
    };
    build_csr(ei_bb, E_BB, NB, off_bb, csr_bb);
    build_csr(ei_sb, E_SB, NB, off_sb, csr_sb);
    build_csr(ei_bs, E_BS, NS, off_bs, csr_bs);

    // ---- layer 0 ----
    agg_mean<<<(NB + 3) / 4, 256, 0, stream>>>(x_b, off_bb, csr_bb, m1, NB);
    agg_mean<<<(NB + 3) / 4, 256, 0, stream>>>(x_s, off_sb, csr_sb, m2, NB);
    agg_mean<<<(NS + 3) / 4, 256, 0, stream>>>(x_b, off_bs, csr_bs, m3, NS);
    gemm_fused<3><<<(NB + 63) / 64, 256, 0, stream>>>(m1, m2, x_b, wb0, bb0, hb, NB);
    gemm_fused<2><<<(NS + 63) / 64, 256, 0, stream>>>(m3, x_s, nullptr, ws0, bs0, m3, NS); // in-place -> h_s

    // ---- layer 1 (seller update is dead code: output only needs x_b) ----
    agg_mean<<<(NB + 3) / 4, 256, 0, stream>>>(hb, off_bb, csr_bb, m1, NB);
    agg_mean<<<(NB + 3) / 4, 256, 0, stream>>>(m3, off_sb, csr_sb, m2, NB);
    gemm_fused<3><<<(NB + 63) / 64, 256, 0, stream>>>(m1, m2, hb, wb1, bb1, m1, NB); // in-place

    // ---- heads ----
    head_kernel<<<(NB + 3) / 4, 256, 0, stream>>>(m1, Wh, bh, out, NB);
}

// Round 8
// 1051.363 us; speedup vs baseline: 42.2986x; 1.3612x over previous
//
#include <hip/hip_runtime.h>

// Problem constants (match reference)
#define NB 100000
#define NS 50000
#define DD 128
constexpr int E_BB = 800000, E_SB = 400000, E_BS = 400000;

// ---------------------------------------------------------------------------
// Weight prep: build concatenated GEMM weights
//   Wb_l [384][128] = [Wl[l,0]; Wl[l,1]; Wr[l,0]+Wr[l,1]]
//   Ws0  [256][128] = [Wl[0,2]; Wr[0,2]]
//   biases: bb_l = bl[l,0]+bl[l,1]; bs0 = bl[0,2]
// ---------------------------------------------------------------------------
__global__ void prep_weights(const float* __restrict__ Wl, const float* __restrict__ bl,
                             const float* __restrict__ Wr,
                             float* __restrict__ wb0, float* __restrict__ wb1,
                             float* __restrict__ ws0,
                             float* __restrict__ bb0, float* __restrict__ bb1,
                             float* __restrict__ bs0) {
    int i = blockIdx.x * blockDim.x + threadIdx.x;
    if (i < 384 * 128) {
        int k = i >> 7, n = i & 127;
        #pragma unroll
        for (int l = 0; l < 2; ++l) {
            float v;
            if (k < 128)      v = Wl[((l*3 + 0)*128 + k)*128 + n];
            else if (k < 256) v = Wl[((l*3 + 1)*128 + (k-128))*128 + n];
            else              v = Wr[((l*3 + 0)*128 + (k-256))*128 + n]
                                + Wr[((l*3 + 1)*128 + (k-256))*128 + n];
            (l ? wb1 : wb0)[i] = v;
        }
    }
    if (i < 256 * 128) {
        int k = i >> 7, n = i & 127;
        ws0[i] = (k < 128) ? Wl[((0*3 + 2)*128 + k)*128 + n]
                           : Wr[((0*3 + 2)*128 + (k-128))*128 + n];
    }
    if (i < 128) {
        bb0[i] = bl[(0*3 + 0)*128 + i] + bl[(0*3 + 1)*128 + i];
        bb1[i] = bl[(1*3 + 0)*128 + i] + bl[(1*3 + 1)*128 + i];
        bs0[i] = bl[(0*3 + 2)*128 + i];
    }
}

// ---------------------------------------------------------------------------
// CSR build: histogram -> hierarchical scan -> atomic-ticket fill
// R4: single-block scan_kernel was 166us x3 (35% of total) at 0.16% occupancy
// (latency chain). Replaced with 3-pass hierarchical scan (~15us per edge type).
// ---------------------------------------------------------------------------
__global__ void hist_kernel(const int* __restrict__ dst, int E, int* __restrict__ off) {
    int i = blockIdx.x * blockDim.x + threadIdx.x;
    if (i < E) {
        int d = dst[i];
        atomicAdd(&off[d + 1], 1);   // cnt lands at off[d+1]; inclusive scan -> exclusive offsets
    }
}

#define SCAN_B 256
// pass 1: per-block sums of 256-element chunks
__global__ __launch_bounds__(SCAN_B)
void scan_blocksums(const int* __restrict__ a, int n, int* __restrict__ bsum) {
    __shared__ int red[SCAN_B];
    int t = threadIdx.x;
    int i = blockIdx.x * SCAN_B + t;
    red[t] = (i < n) ? a[i] : 0;
    __syncthreads();
    #pragma unroll
    for (int d = SCAN_B / 2; d > 0; d >>= 1) {
        if (t < d) red[t] += red[t + d];
        __syncthreads();
    }
    if (t == 0) bsum[blockIdx.x] = red[0];
}

// pass 2: single block, exclusive scan of <=1024 block sums (in place)
__global__ __launch_bounds__(1024)
void scan_bsum_exclusive(int* __restrict__ bsum, int nb) {
    __shared__ int s[1024];
    int t = threadIdx.x;
    s[t] = (t < nb) ? bsum[t] : 0;
    __syncthreads();
    for (int d = 1; d < 1024; d <<= 1) {
        int u = (t >= d) ? s[t - d] : 0;
        __syncthreads();
        s[t] += u;
        __syncthreads();
    }
    if (t < nb) bsum[t] = (t == 0) ? 0 : s[t - 1];
}

// pass 3: per-block inclusive scan + exclusive block offset, in place
__global__ __launch_bounds__(SCAN_B)
void scan_apply(int* __restrict__ a, int n, const int* __restrict__ bsum) {
    __shared__ int s[SCAN_B];
    int t = threadIdx.x;
    int i = blockIdx.x * SCAN_B + t;
    int v = (i < n) ? a[i] : 0;
    s[t] = v;
    __syncthreads();
    #pragma unroll
    for (int d = 1; d < SCAN_B; d <<= 1) {
        int u = (t >= d) ? s[t - d] : 0;
        __syncthreads();
        s[t] += u;
        __syncthreads();
    }
    if (i < n) a[i] = s[t] + bsum[blockIdx.x];
}

__global__ void fill_kernel(const int* __restrict__ src, const int* __restrict__ dst, int E,
                            const int* __restrict__ off, int* __restrict__ tick,
                            int* __restrict__ csr) {
    int i = blockIdx.x * blockDim.x + threadIdx.x;
    if (i < E) {
        int d = dst[i];
        int pos = off[d] + atomicAdd(&tick[d], 1);
        csr[pos] = src[i];
    }
}

// ---------------------------------------------------------------------------
// Mean aggregation: one 64-lane wave per dst node, float2 per lane (512B/row)
// ---------------------------------------------------------------------------
__global__ __launch_bounds__(256)
void agg_mean(const float* __restrict__ xsrc, const int* __restrict__ off,
              const int* __restrict__ csr, float* __restrict__ out, int n) {
    int node = blockIdx.x * 4 + (threadIdx.x >> 6);
    if (node >= n) return;
    int lane = threadIdx.x & 63;
    int s = off[node], e = off[node + 1];
    float ax = 0.f, ay = 0.f;
    for (int p = s; p < e; ++p) {
        int j = csr[p];
        float2 v = *(const float2*)&xsrc[(size_t)j * DD + lane * 2];
        ax += v.x; ay += v.y;
    }
    float inv = 1.0f / fmaxf((float)(e - s), 1.0f);
    float2 r; r.x = ax * inv; r.y = ay * inv;
    *(float2*)&out[(size_t)node * DD + lane * 2] = r;
}

// ---------------------------------------------------------------------------
// Fused GEMM: out = leakyrelu([A0|A1|A2] @ W + bias), W prepped [KTILES*128][128]
// BM=64, BN=128, BK=32, 256 threads; thread tile 4x8.
// R2 spill fix: unroll 1 on tile loops + __launch_bounds__(256,4); verified R4:
// 31x total speedup, gemms no longer in top-5. In-place-safe.
// ---------------------------------------------------------------------------
template<int KTILES>
__global__ __launch_bounds__(256, 4)
void gemm_fused(const float* __restrict__ A0, const float* __restrict__ A1,
                const float* __restrict__ A2,
                const float* __restrict__ W, const float* __restrict__ bias,
                float* __restrict__ out, int M) {
    __shared__ float As[32][68];    // transposed A-tile [k][m], padded
    __shared__ float Bs[32][132];   // B-tile [k][n], padded
    const int tid = threadIdx.x;
    const int tx = tid & 15;        // col group: cols tx*8..+8
    const int ty = tid >> 4;        // row group: rows ty*4..+4
    const int rowbase = blockIdx.x * 64;
    float acc[4][8] = {};

    #pragma unroll 1
    for (int s = 0; s < KTILES; ++s) {
        const float* A = (s == 0) ? A0 : (s == 1) ? A1 : A2;   // uniform scalar select
        #pragma unroll 1
        for (int q = 0; q < 4; ++q) {
            const int k0 = q * 32;
            const int ktile = s * 4 + q;
            // A-tile: 64 rows x 32 k = 512 float4, 2 per thread, store transposed
            #pragma unroll
            for (int f = 0; f < 2; ++f) {
                int fid = tid + f * 256;
                int r = fid >> 3, kq = fid & 7;
                int row = rowbase + r;
                float4 v = make_float4(0.f, 0.f, 0.f, 0.f);
                if (row < M) v = *(const float4*)&A[(size_t)row * DD + k0 + kq * 4];
                As[kq*4+0][r] = v.x; As[kq*4+1][r] = v.y;
                As[kq*4+2][r] = v.z; As[kq*4+3][r] = v.w;
            }
            // B-tile: 32 k x 128 n = 1024 float4, 4 per thread
            #pragma unroll
            for (int f = 0; f < 4; ++f) {
                int fid = tid + f * 256;
                int kk = fid >> 5, nq = fid & 31;
                *(float4*)&Bs[kk][nq * 4] = *(const float4*)&W[(size_t)(ktile * 32 + kk) * 128 + nq * 4];
            }
            __syncthreads();
            #pragma unroll 8
            for (int k = 0; k < 32; ++k) {
                float4 a  = *(const float4*)&As[k][ty * 4];
                float4 b0 = *(const float4*)&Bs[k][tx * 8];
                float4 b1 = *(const float4*)&Bs[k][tx * 8 + 4];
                float av[4] = {a.x, a.y, a.z, a.w};
                float bv[8] = {b0.x, b0.y, b0.z, b0.w, b1.x, b1.y, b1.z, b1.w};
                #pragma unroll
                for (int i = 0; i < 4; ++i)
                    #pragma unroll
                    for (int j = 0; j < 8; ++j)
                        acc[i][j] += av[i] * bv[j];
            }
            __syncthreads();
        }
    }
    #pragma unroll
    for (int i = 0; i < 4; ++i) {
        int row = rowbase + ty * 4 + i;
        if (row < M) {
            #pragma unroll
            for (int j = 0; j < 8; ++j) {
                float v = acc[i][j] + bias[tx * 8 + j];
                v = (v > 0.f) ? v : 0.01f * v;
                out[(size_t)row * 128 + tx * 8 + j] = v;
            }
        }
    }
}

// ---------------------------------------------------------------------------
// Head: out[i,h] = sum_c x[i,c]*Wh[h,c] + bh[h]; one wave per row
// ---------------------------------------------------------------------------
__global__ __launch_bounds__(256)
void head_kernel(const float* __restrict__ x, const float* __restrict__ Wh,
                 const float* __restrict__ bh, float* __restrict__ out, int M) {
    __shared__ float w[8][128];
    int tid = threadIdx.x;
    for (int i = tid; i < 1024; i += 256) w[i >> 7][i & 127] = Wh[i];
    __syncthreads();
    int row = blockIdx.x * 4 + (tid >> 6);
    if (row >= M) return;
    int lane = tid & 63;
    float2 v = *(const float2*)&x[(size_t)row * DD + lane * 2];
    float acc[8];
    #pragma unroll
    for (int h = 0; h < 8; ++h)
        acc[h] = v.x * w[h][lane * 2] + v.y * w[h][lane * 2 + 1];
    #pragma unroll
    for (int h = 0; h < 8; ++h) {
        float s = acc[h];
        #pragma unroll
        for (int d = 32; d >= 1; d >>= 1) s += __shfl_xor(s, d);
        acc[h] = s;
    }
    if (lane == 0) {
        #pragma unroll
        for (int h = 0; h < 8; ++h) out[(size_t)row * 8 + h] = acc[h] + bh[h];
    }
}

// ---------------------------------------------------------------------------
extern "C" void kernel_launch(void* const* d_in, const int* in_sizes, int n_in,
                              void* d_out, int out_size, void* d_ws, size_t ws_size,
                              hipStream_t stream) {
    const float* x_b = (const float*)d_in[0];
    const float* x_s = (const float*)d_in[1];
    const float* Wl  = (const float*)d_in[2];
    const float* bl  = (const float*)d_in[3];
    const float* Wr  = (const float*)d_in[4];
    const float* Wh  = (const float*)d_in[5];
    const float* bh  = (const float*)d_in[6];
    const int* ei_bb = (const int*)d_in[7];
    const int* ei_sb = (const int*)d_in[8];
    const int* ei_bs = (const int*)d_in[9];
    float* out = (float*)d_out;

    char* p = (char*)d_ws;
    auto alloc = [&](size_t bytes) { char* r = p; p += (bytes + 255) & ~255ull; return r; };
    int* off_bb = (int*)alloc((NB + 1) * 4);
    int* off_sb = (int*)alloc((NB + 1) * 4);
    int* off_bs = (int*)alloc((NS + 1) * 4);
    int* csr_bb = (int*)alloc((size_t)E_BB * 4);
    int* csr_sb = (int*)alloc((size_t)E_SB * 4);
    int* csr_bs = (int*)alloc((size_t)E_BS * 4);
    int* tick   = (int*)alloc((size_t)NB * 4);
    int* bsum   = (int*)alloc(1024 * 4);
    float* m1  = (float*)alloc((size_t)NB * 128 * 4);
    float* m2  = (float*)alloc((size_t)NB * 128 * 4);
    float* m3  = (float*)alloc((size_t)NS * 128 * 4);
    float* hb  = (float*)alloc((size_t)NB * 128 * 4);
    float* wb0 = (float*)alloc(384 * 128 * 4);
    float* wb1 = (float*)alloc(384 * 128 * 4);
    float* ws0 = (float*)alloc(256 * 128 * 4);
    float* bb0 = (float*)alloc(128 * 4);
    float* bb1 = (float*)alloc(128 * 4);
    float* bs0 = (float*)alloc(128 * 4);

    prep_weights<<<192, 256, 0, stream>>>(Wl, bl, Wr, wb0, wb1, ws0, bb0, bb1, bs0);

    auto build_csr = [&](const int* ei, int E, int n, int* off, int* csr) {
        hipMemsetAsync(off, 0, (size_t)(n + 1) * 4, stream);
        hist_kernel<<<(E + 255) / 256, 256, 0, stream>>>(ei + E, E, off);
        int n1 = n + 1;
        int nb = (n1 + SCAN_B - 1) / SCAN_B;   // <=391 <=1024
        scan_blocksums<<<nb, SCAN_B, 0, stream>>>(off, n1, bsum);
        scan_bsum_exclusive<<<1, 1024, 0, stream>>>(bsum, nb);
        scan_apply<<<nb, SCAN_B, 0, stream>>>(off, n1, bsum);
        hipMemsetAsync(tick, 0, (size_t)n * 4, stream);
        fill_kernel<<<(E + 255) / 256, 256, 0, stream>>>(ei, ei + E, E, off, tick, csr);
    };
    build_csr(ei_bb, E_BB, NB, off_bb, csr_bb);
    build_csr(ei_sb, E_SB, NB, off_sb, csr_sb);
    build_csr(ei_bs, E_BS, NS, off_bs, csr_bs);

    // ---- layer 0 ----
    agg_mean<<<(NB + 3) / 4, 256, 0, stream>>>(x_b, off_bb, csr_bb, m1, NB);
    agg_mean<<<(NB + 3) / 4, 256, 0, stream>>>(x_s, off_sb, csr_sb, m2, NB);
    agg_mean<<<(NS + 3) / 4, 256, 0, stream>>>(x_b, off_bs, csr_bs, m3, NS);
    gemm_fused<3><<<(NB + 63) / 64, 256, 0, stream>>>(m1, m2, x_b, wb0, bb0, hb, NB);
    gemm_fused<2><<<(NS + 63) / 64, 256, 0, stream>>>(m3, x_s, nullptr, ws0, bs0, m3, NS); // in-place -> h_s

    // ---- layer 1 (seller update is dead code: output only needs x_b) ----
    agg_mean<<<(NB + 3) / 4, 256, 0, stream>>>(hb, off_bb, csr_bb, m1, NB);
    agg_mean<<<(NB + 3) / 4, 256, 0, stream>>>(m3, off_sb, csr_sb, m2, NB);
    gemm_fused<3><<<(NB + 63) / 64, 256, 0, stream>>>(m1, m2, hb, wb1, bb1, m1, NB); // in-place

    // ---- heads ----
    head_kernel<<<(NB + 3) / 4, 256, 0, stream>>>(m1, Wh, bh, out, NB);
}

// Round 9
// 866.211 us; speedup vs baseline: 51.3399x; 1.2137x over previous
//
#include <hip/hip_runtime.h>

// Problem constants (match reference)
#define NB 100000
#define NS 50000
#define DD 128
constexpr int E_BB = 800000, E_SB = 400000, E_BS = 400000;

typedef __attribute__((ext_vector_type(8))) short bf16x8;
typedef __attribute__((ext_vector_type(4))) float f32x4;

__device__ inline unsigned short f2bf(float f) {    // fp32 -> bf16 RNE
    unsigned int u = __float_as_uint(f);
    u += 0x7FFF + ((u >> 16) & 1);
    return (unsigned short)(u >> 16);
}

// ---------------------------------------------------------------------------
// Weight prep (R8: bf16, transposed [n][k] for MFMA B staging)
//   wt_l [128 n][384 k] = [Wl[l,0]; Wl[l,1]; Wr[l,0]+Wr[l,1]]^T
//   wts  [128 n][256 k] = [Wl[0,2]; Wr[0,2]]^T
//   biases fp32: bb_l = bl[l,0]+bl[l,1]; bs0 = bl[0,2]
// ---------------------------------------------------------------------------
__global__ void prep_weights(const float* __restrict__ Wl, const float* __restrict__ bl,
                             const float* __restrict__ Wr,
                             unsigned short* __restrict__ wt0, unsigned short* __restrict__ wt1,
                             unsigned short* __restrict__ wts,
                             float* __restrict__ bb0, float* __restrict__ bb1,
                             float* __restrict__ bs0) {
    int i = blockIdx.x * blockDim.x + threadIdx.x;
    if (i < 128 * 384) {
        int n = i / 384, k = i % 384;
        #pragma unroll
        for (int l = 0; l < 2; ++l) {
            float v;
            if (k < 128)      v = Wl[((l*3 + 0)*128 + k)*128 + n];
            else if (k < 256) v = Wl[((l*3 + 1)*128 + (k-128))*128 + n];
            else              v = Wr[((l*3 + 0)*128 + (k-256))*128 + n]
                                + Wr[((l*3 + 1)*128 + (k-256))*128 + n];
            (l ? wt1 : wt0)[i] = f2bf(v);
        }
    }
    if (i < 128 * 256) {
        int n = i / 256, k = i % 256;
        float v = (k < 128) ? Wl[((0*3 + 2)*128 + k)*128 + n]
                            : Wr[((0*3 + 2)*128 + (k-128))*128 + n];
        wts[i] = f2bf(v);
    }
    if (i < 128) {
        bb0[i] = bl[(0*3 + 0)*128 + i] + bl[(0*3 + 1)*128 + i];
        bb1[i] = bl[(1*3 + 0)*128 + i] + bl[(1*3 + 1)*128 + i];
        bs0[i] = bl[(0*3 + 2)*128 + i];
    }
}

// ---------------------------------------------------------------------------
// CSR build: histogram -> hierarchical scan -> atomic-ticket fill
// R4: single-block scan was 166us x3 at 0.16% occupancy; 3-pass scan fixed it
// (verified R8: scans gone from top-5, total 1431 -> 1051us).
// ---------------------------------------------------------------------------
__global__ void hist_kernel(const int* __restrict__ dst, int E, int* __restrict__ off) {
    int i = blockIdx.x * blockDim.x + threadIdx.x;
    if (i < E) {
        int d = dst[i];
        atomicAdd(&off[d + 1], 1);
    }
}

#define SCAN_B 256
__global__ __launch_bounds__(SCAN_B)
void scan_blocksums(const int* __restrict__ a, int n, int* __restrict__ bsum) {
    __shared__ int red[SCAN_B];
    int t = threadIdx.x;
    int i = blockIdx.x * SCAN_B + t;
    red[t] = (i < n) ? a[i] : 0;
    __syncthreads();
    #pragma unroll
    for (int d = SCAN_B / 2; d > 0; d >>= 1) {
        if (t < d) red[t] += red[t + d];
        __syncthreads();
    }
    if (t == 0) bsum[blockIdx.x] = red[0];
}

__global__ __launch_bounds__(1024)
void scan_bsum_exclusive(int* __restrict__ bsum, int nb) {
    __shared__ int s[1024];
    int t = threadIdx.x;
    s[t] = (t < nb) ? bsum[t] : 0;
    __syncthreads();
    for (int d = 1; d < 1024; d <<= 1) {
        int u = (t >= d) ? s[t - d] : 0;
        __syncthreads();
        s[t] += u;
        __syncthreads();
    }
    if (t < nb) bsum[t] = (t == 0) ? 0 : s[t - 1];
}

__global__ __launch_bounds__(SCAN_B)
void scan_apply(int* __restrict__ a, int n, const int* __restrict__ bsum) {
    __shared__ int s[SCAN_B];
    int t = threadIdx.x;
    int i = blockIdx.x * SCAN_B + t;
    int v = (i < n) ? a[i] : 0;
    s[t] = v;
    __syncthreads();
    #pragma unroll
    for (int d = 1; d < SCAN_B; d <<= 1) {
        int u = (t >= d) ? s[t - d] : 0;
        __syncthreads();
        s[t] += u;
        __syncthreads();
    }
    if (i < n) a[i] = s[t] + bsum[blockIdx.x];
}

__global__ void fill_kernel(const int* __restrict__ src, const int* __restrict__ dst, int E,
                            const int* __restrict__ off, int* __restrict__ tick,
                            int* __restrict__ csr) {
    int i = blockIdx.x * blockDim.x + threadIdx.x;
    if (i < E) {
        int d = dst[i];
        int pos = off[d] + atomicAdd(&tick[d], 1);
        csr[pos] = src[i];
    }
}

// ---------------------------------------------------------------------------
// Mean aggregation: one 64-lane wave per dst node, float2 per lane (512B/row)
// ---------------------------------------------------------------------------
__global__ __launch_bounds__(256)
void agg_mean(const float* __restrict__ xsrc, const int* __restrict__ off,
              const int* __restrict__ csr, float* __restrict__ out, int n) {
    int node = blockIdx.x * 4 + (threadIdx.x >> 6);
    if (node >= n) return;
    int lane = threadIdx.x & 63;
    int s = off[node], e = off[node + 1];
    float ax = 0.f, ay = 0.f;
    for (int p = s; p < e; ++p) {
        int j = csr[p];
        float2 v = *(const float2*)&xsrc[(size_t)j * DD + lane * 2];
        ax += v.x; ay += v.y;
    }
    float inv = 1.0f / fmaxf((float)(e - s), 1.0f);
    float2 r; r.x = ax * inv; r.y = ay * inv;
    *(float2*)&out[(size_t)node * DD + lane * 2] = r;
}

// ---------------------------------------------------------------------------
// MFMA GEMM (R8): out = leakyrelu([A0|A1|A2]@W + bias), W bf16-transposed [n][k].
// R8 evidence: fp32 VALU gemm was 159us at 62TF (39% of 157TF vector, MfmaUtil 0,
// 2.28e7 bank conflicts). bf16 matrix pipe = 2.5PF; expected HBM-bound ~35-45us.
// BM=128, 4 waves x 32 rows, per-wave 2x8 frags of 16x16x32.
// A staged fp32->bf16 RNE in LDS; fragment reads are contiguous 1KB/wave
// (conflict-free). fp32 accum + fp32 bias/leaky/store. In-place-safe
// (block reads only its own 128 output rows; writes after k-loop).
// Layouts (m89-verified): A row=lane&15, k=(lane>>4)*8+j; B col=lane&15;
// D row=(lane>>4)*4+reg, col=lane&15.
// ---------------------------------------------------------------------------
template<int KTILES>
__global__ __launch_bounds__(256)
void gemm_mfma(const float* __restrict__ A0, const float* __restrict__ A1,
               const float* __restrict__ A2, const unsigned short* __restrict__ Wt,
               const float* __restrict__ bias, float* __restrict__ out, int M) {
    constexpr int K = KTILES * 128;
    __shared__ unsigned short As[128][32];   // [m][k] bf16, 8KB
    __shared__ unsigned short Bs[128][32];   // [n][k] bf16, 8KB
    const int tid = threadIdx.x;
    const int lane = tid & 63;
    const int w = tid >> 6;            // wave 0..3 -> rows w*32..+32
    const int rowbase = blockIdx.x * 128;
    const int m16 = lane & 15;
    const int kg  = lane >> 4;         // k-group 0..3

    f32x4 acc[2][8] = {};

    #pragma unroll 1
    for (int s = 0; s < KTILES; ++s) {
        const float* A = (s == 0) ? A0 : (s == 1) ? A1 : A2;
        #pragma unroll 1
        for (int q = 0; q < 4; ++q) {
            const int k0 = s * 128 + q * 32;     // k into Wt
            // stage A: 128 rows x 32 k fp32 -> bf16 (1024 float4, 4/thread)
            #pragma unroll
            for (int f = 0; f < 4; ++f) {
                int fid = tid + f * 256;
                int r = fid >> 3, c4 = fid & 7;
                int row = rowbase + r;
                float4 v = make_float4(0.f, 0.f, 0.f, 0.f);
                if (row < M) v = *(const float4*)&A[(size_t)row * DD + q * 32 + c4 * 4];
                ushort4 sv;
                sv.x = f2bf(v.x); sv.y = f2bf(v.y); sv.z = f2bf(v.z); sv.w = f2bf(v.w);
                *(ushort4*)&As[r][c4 * 4] = sv;
            }
            // stage B: Bs[n][0..32) = Wt[n][k0..k0+32) (512 x 16B, 2/thread)
            #pragma unroll
            for (int f = 0; f < 2; ++f) {
                int fid = tid + f * 256;
                int n = fid >> 2, sg = fid & 3;
                *(uint4*)&Bs[n][sg * 8] = *(const uint4*)&Wt[(size_t)n * K + k0 + sg * 8];
            }
            __syncthreads();
            bf16x8 af[2];
            #pragma unroll
            for (int mf = 0; mf < 2; ++mf)
                af[mf] = *(const bf16x8*)&As[w * 32 + mf * 16 + m16][kg * 8];
            #pragma unroll
            for (int nf = 0; nf < 8; ++nf) {
                bf16x8 bfr = *(const bf16x8*)&Bs[nf * 16 + m16][kg * 8];
                #pragma unroll
                for (int mf = 0; mf < 2; ++mf)
                    acc[mf][nf] = __builtin_amdgcn_mfma_f32_16x16x32_bf16(af[mf], bfr, acc[mf][nf], 0, 0, 0);
            }
            __syncthreads();
        }
    }
    // epilogue: bias + leaky-relu, fp32 store
    #pragma unroll
    for (int mf = 0; mf < 2; ++mf) {
        #pragma unroll
        for (int nf = 0; nf < 8; ++nf) {
            int col = nf * 16 + m16;
            float bv = bias[col];
            #pragma unroll
            for (int r = 0; r < 4; ++r) {
                int row = rowbase + w * 32 + mf * 16 + kg * 4 + r;
                if (row < M) {
                    float v = acc[mf][nf][r] + bv;
                    v = (v > 0.f) ? v : 0.01f * v;
                    out[(size_t)row * 128 + col] = v;
                }
            }
        }
    }
}

// ---------------------------------------------------------------------------
// Head: out[i,h] = sum_c x[i,c]*Wh[h,c] + bh[h]; one wave per row
// ---------------------------------------------------------------------------
__global__ __launch_bounds__(256)
void head_kernel(const float* __restrict__ x, const float* __restrict__ Wh,
                 const float* __restrict__ bh, float* __restrict__ out, int M) {
    __shared__ float w[8][128];
    int tid = threadIdx.x;
    for (int i = tid; i < 1024; i += 256) w[i >> 7][i & 127] = Wh[i];
    __syncthreads();
    int row = blockIdx.x * 4 + (tid >> 6);
    if (row >= M) return;
    int lane = tid & 63;
    float2 v = *(const float2*)&x[(size_t)row * DD + lane * 2];
    float acc[8];
    #pragma unroll
    for (int h = 0; h < 8; ++h)
        acc[h] = v.x * w[h][lane * 2] + v.y * w[h][lane * 2 + 1];
    #pragma unroll
    for (int h = 0; h < 8; ++h) {
        float s = acc[h];
        #pragma unroll
        for (int d = 32; d >= 1; d >>= 1) s += __shfl_xor(s, d);
        acc[h] = s;
    }
    if (lane == 0) {
        #pragma unroll
        for (int h = 0; h < 8; ++h) out[(size_t)row * 8 + h] = acc[h] + bh[h];
    }
}

// ---------------------------------------------------------------------------
extern "C" void kernel_launch(void* const* d_in, const int* in_sizes, int n_in,
                              void* d_out, int out_size, void* d_ws, size_t ws_size,
                              hipStream_t stream) {
    const float* x_b = (const float*)d_in[0];
    const float* x_s = (const float*)d_in[1];
    const float* Wl  = (const float*)d_in[2];
    const float* bl  = (const float*)d_in[3];
    const float* Wr  = (const float*)d_in[4];
    const float* Wh  = (const float*)d_in[5];
    const float* bh  = (const float*)d_in[6];
    const int* ei_bb = (const int*)d_in[7];
    const int* ei_sb = (const int*)d_in[8];
    const int* ei_bs = (const int*)d_in[9];
    float* out = (float*)d_out;

    char* p = (char*)d_ws;
    auto alloc = [&](size_t bytes) { char* r = p; p += (bytes + 255) & ~255ull; return r; };
    int* off_bb = (int*)alloc((NB + 1) * 4);
    int* off_sb = (int*)alloc((NB + 1) * 4);
    int* off_bs = (int*)alloc((NS + 1) * 4);
    int* csr_bb = (int*)alloc((size_t)E_BB * 4);
    int* csr_sb = (int*)alloc((size_t)E_SB * 4);
    int* csr_bs = (int*)alloc((size_t)E_BS * 4);
    int* tick   = (int*)alloc((size_t)NB * 4);
    int* bsum   = (int*)alloc(1024 * 4);
    float* m1  = (float*)alloc((size_t)NB * 128 * 4);
    float* m2  = (float*)alloc((size_t)NB * 128 * 4);
    float* m3  = (float*)alloc((size_t)NS * 128 * 4);
    float* hb  = (float*)alloc((size_t)NB * 128 * 4);
    unsigned short* wt0 = (unsigned short*)alloc(128 * 384 * 2);
    unsigned short* wt1 = (unsigned short*)alloc(128 * 384 * 2);
    unsigned short* wts = (unsigned short*)alloc(128 * 256 * 2);
    float* bb0 = (float*)alloc(128 * 4);
    float* bb1 = (float*)alloc(128 * 4);
    float* bs0 = (float*)alloc(128 * 4);

    prep_weights<<<192, 256, 0, stream>>>(Wl, bl, Wr, wt0, wt1, wts, bb0, bb1, bs0);

    auto build_csr = [&](const int* ei, int E, int n, int* off, int* csr) {
        hipMemsetAsync(off, 0, (size_t)(n + 1) * 4, stream);
        hist_kernel<<<(E + 255) / 256, 256, 0, stream>>>(ei + E, E, off);
        int n1 = n + 1;
        int nb = (n1 + SCAN_B - 1) / SCAN_B;   // <=391 <=1024
        scan_blocksums<<<nb, SCAN_B, 0, stream>>>(off, n1, bsum);
        scan_bsum_exclusive<<<1, 1024, 0, stream>>>(bsum, nb);
        scan_apply<<<nb, SCAN_B, 0, stream>>>(off, n1, bsum);
        hipMemsetAsync(tick, 0, (size_t)n * 4, stream);
        fill_kernel<<<(E + 255) / 256, 256, 0, stream>>>(ei, ei + E, E, off, tick, csr);
    };
    build_csr(ei_bb, E_BB, NB, off_bb, csr_bb);
    build_csr(ei_sb, E_SB, NB, off_sb, csr_sb);
    build_csr(ei_bs, E_BS, NS, off_bs, csr_bs);

    // ---- layer 0 ----
    agg_mean<<<(NB + 3) / 4, 256, 0, stream>>>(x_b, off_bb, csr_bb, m1, NB);
    agg_mean<<<(NB + 3) / 4, 256, 0, stream>>>(x_s, off_sb, csr_sb, m2, NB);
    agg_mean<<<(NS + 3) / 4, 256, 0, stream>>>(x_b, off_bs, csr_bs, m3, NS);
    gemm_mfma<3><<<(NB + 127) / 128, 256, 0, stream>>>(m1, m2, x_b, wt0, bb0, hb, NB);
    gemm_mfma<2><<<(NS + 127) / 128, 256, 0, stream>>>(m3, x_s, nullptr, wts, bs0, m3, NS); // in-place -> h_s

    // ---- layer 1 (seller update is dead code: output only needs x_b) ----
    agg_mean<<<(NB + 3) / 4, 256, 0, stream>>>(hb, off_bb, csr_bb, m1, NB);
    agg_mean<<<(NB + 3) / 4, 256, 0, stream>>>(m3, off_sb, csr_sb, m2, NB);
    gemm_mfma<3><<<(NB + 127) / 128, 256, 0, stream>>>(m1, m2, hb, wt1, bb1, m1, NB); // in-place

    // ---- heads ----
    head_kernel<<<(NB + 3) / 4, 256, 0, stream>>>(m1, Wh, bh, out, NB);
}

// Round 11
// 792.143 us; speedup vs baseline: 56.1404x; 1.0935x over previous
//
#include <hip/hip_runtime.h>

// Problem constants (match reference)
#define NB 100000
#define NS 50000
#define DD 128
constexpr int E_BB = 800000, E_SB = 400000, E_BS = 400000;

typedef __attribute__((ext_vector_type(8))) short bf16x8;
typedef __attribute__((ext_vector_type(4))) float f32x4;

__device__ inline unsigned short f2bf(float f) {    // fp32 -> bf16 RNE
    unsigned int u = __float_as_uint(f);
    u += 0x7FFF + ((u >> 16) & 1);
    return (unsigned short)(u >> 16);
}
__device__ inline float bf2f(unsigned int lo16) {   // bf16 (low 16 bits) -> fp32
    return __uint_as_float(lo16 << 16);
}

// ---------------------------------------------------------------------------
// fp32 -> bf16 feature conversion (R9: halve all gather/agg/GEMM-A traffic;
// GEMM staging already rounded A to bf16, so precision structure unchanged)
// ---------------------------------------------------------------------------
__global__ __launch_bounds__(256)
void cvt_bf16(const float* __restrict__ in, unsigned short* __restrict__ out, int n4) {
    int i = blockIdx.x * blockDim.x + threadIdx.x;
    if (i < n4) {
        float4 v = *(const float4*)&in[i * 4];
        ushort4 s;
        s.x = f2bf(v.x); s.y = f2bf(v.y); s.z = f2bf(v.z); s.w = f2bf(v.w);
        *(ushort4*)&out[i * 4] = s;
    }
}

// ---------------------------------------------------------------------------
// Weight prep (bf16, transposed [n][k] for MFMA B staging)
// ---------------------------------------------------------------------------
__global__ void prep_weights(const float* __restrict__ Wl, const float* __restrict__ bl,
                             const float* __restrict__ Wr,
                             unsigned short* __restrict__ wt0, unsigned short* __restrict__ wt1,
                             unsigned short* __restrict__ wts,
                             float* __restrict__ bb0, float* __restrict__ bb1,
                             float* __restrict__ bs0) {
    int i = blockIdx.x * blockDim.x + threadIdx.x;
    if (i < 128 * 384) {
        int n = i / 384, k = i % 384;
        #pragma unroll
        for (int l = 0; l < 2; ++l) {
            float v;
            if (k < 128)      v = Wl[((l*3 + 0)*128 + k)*128 + n];
            else if (k < 256) v = Wl[((l*3 + 1)*128 + (k-128))*128 + n];
            else              v = Wr[((l*3 + 0)*128 + (k-256))*128 + n]
                                + Wr[((l*3 + 1)*128 + (k-256))*128 + n];
            (l ? wt1 : wt0)[i] = f2bf(v);
        }
    }
    if (i < 128 * 256) {
        int n = i / 256, k = i % 256;
        float v = (k < 128) ? Wl[((0*3 + 2)*128 + k)*128 + n]
                            : Wr[((0*3 + 2)*128 + (k-128))*128 + n];
        wts[i] = f2bf(v);
    }
    if (i < 128) {
        bb0[i] = bl[(0*3 + 0)*128 + i] + bl[(0*3 + 1)*128 + i];
        bb1[i] = bl[(1*3 + 0)*128 + i] + bl[(1*3 + 1)*128 + i];
        bs0[i] = bl[(0*3 + 2)*128 + i];
    }
}

// ---------------------------------------------------------------------------
// CSR build: histogram -> 3-pass hierarchical scan -> atomic-ticket fill
// (R4 evidence: single-block scan was 35% of total; fixed+verified R8)
// ---------------------------------------------------------------------------
__global__ void hist_kernel(const int* __restrict__ dst, int E, int* __restrict__ off) {
    int i = blockIdx.x * blockDim.x + threadIdx.x;
    if (i < E) {
        int d = dst[i];
        atomicAdd(&off[d + 1], 1);
    }
}

#define SCAN_B 256
__global__ __launch_bounds__(SCAN_B)
void scan_blocksums(const int* __restrict__ a, int n, int* __restrict__ bsum) {
    __shared__ int red[SCAN_B];
    int t = threadIdx.x;
    int i = blockIdx.x * SCAN_B + t;
    red[t] = (i < n) ? a[i] : 0;
    __syncthreads();
    #pragma unroll
    for (int d = SCAN_B / 2; d > 0; d >>= 1) {
        if (t < d) red[t] += red[t + d];
        __syncthreads();
    }
    if (t == 0) bsum[blockIdx.x] = red[0];
}

__global__ __launch_bounds__(1024)
void scan_bsum_exclusive(int* __restrict__ bsum, int nb) {
    __shared__ int s[1024];
    int t = threadIdx.x;
    s[t] = (t < nb) ? bsum[t] : 0;
    __syncthreads();
    for (int d = 1; d < 1024; d <<= 1) {
        int u = (t >= d) ? s[t - d] : 0;
        __syncthreads();
        s[t] += u;
        __syncthreads();
    }
    if (t < nb) bsum[t] = (t == 0) ? 0 : s[t - 1];
}

__global__ __launch_bounds__(SCAN_B)
void scan_apply(int* __restrict__ a, int n, const int* __restrict__ bsum) {
    __shared__ int s[SCAN_B];
    int t = threadIdx.x;
    int i = blockIdx.x * SCAN_B + t;
    int v = (i < n) ? a[i] : 0;
    s[t] = v;
    __syncthreads();
    #pragma unroll
    for (int d = 1; d < SCAN_B; d <<= 1) {
        int u = (t >= d) ? s[t - d] : 0;
        __syncthreads();
        s[t] += u;
        __syncthreads();
    }
    if (i < n) a[i] = s[t] + bsum[blockIdx.x];
}

__global__ void fill_kernel(const int* __restrict__ src, const int* __restrict__ dst, int E,
                            const int* __restrict__ off, int* __restrict__ tick,
                            int* __restrict__ csr) {
    int i = blockIdx.x * blockDim.x + threadIdx.x;
    if (i < E) {
        int d = dst[i];
        int pos = off[d] + atomicAdd(&tick[d], 1);
        csr[pos] = src[i];
    }
}

// ---------------------------------------------------------------------------
// Mean aggregation over bf16 features: one wave per dst node, uint (2 bf16)
// per lane = 256B/row gather; fp32 accumulate; bf16 store.
// R9 evidence: fp32 agg = 103us @ FETCH 191MB (2.4TB/s, 29% peak) -> bytes-bound.
// ---------------------------------------------------------------------------
__global__ __launch_bounds__(256)
void agg_mean_bf16(const unsigned short* __restrict__ xsrc, const int* __restrict__ off,
                   const int* __restrict__ csr, unsigned short* __restrict__ out, int n) {
    int node = blockIdx.x * 4 + (threadIdx.x >> 6);
    if (node >= n) return;
    int lane = threadIdx.x & 63;
    int s = off[node], e = off[node + 1];
    float ax = 0.f, ay = 0.f;
    for (int p = s; p < e; ++p) {
        int j = csr[p];
        unsigned int v = *(const unsigned int*)&xsrc[(size_t)j * DD + lane * 2];
        ax += bf2f(v & 0xFFFFu);
        ay += bf2f(v >> 16);
    }
    float inv = 1.0f / fmaxf((float)(e - s), 1.0f);
    unsigned int r = ((unsigned int)f2bf(ay * inv) << 16) | (unsigned int)f2bf(ax * inv);
    *(unsigned int*)&out[(size_t)node * DD + lane * 2] = r;
}

// ---------------------------------------------------------------------------
// MFMA GEMM: out(bf16) = leakyrelu([A0|A1|A2](bf16)@W + bias).
// R8->R9 verified: MFMA moved gemms out of top-5. Now A is bf16: staging is a
// plain 16B copy (no cvt), A-fetch halved. BM=128, 4 waves x 32 rows,
// per-wave 2x8 frags of 16x16x32; fp32 accum; bf16 epilogue store.
// In-place-safe (block reads only its own 128 output rows; writes after k-loop).
// Layouts (m89-verified): A row=lane&15, k=(lane>>4)*8+j; B col=lane&15;
// D row=(lane>>4)*4+reg, col=lane&15.
// ---------------------------------------------------------------------------
template<int KTILES>
__global__ __launch_bounds__(256)
void gemm_mfma(const unsigned short* __restrict__ A0, const unsigned short* __restrict__ A1,
               const unsigned short* __restrict__ A2, const unsigned short* __restrict__ Wt,
               const float* __restrict__ bias, unsigned short* __restrict__ out, int M) {
    constexpr int K = KTILES * 128;
    __shared__ unsigned short As[128][32];   // [m][k] bf16, 8KB
    __shared__ unsigned short Bs[128][32];   // [n][k] bf16, 8KB
    const int tid = threadIdx.x;
    const int lane = tid & 63;
    const int w = tid >> 6;            // wave 0..3 -> rows w*32..+32
    const int rowbase = blockIdx.x * 128;
    const int m16 = lane & 15;
    const int kg  = lane >> 4;         // k-group 0..3

    f32x4 acc[2][8] = {};

    #pragma unroll 1
    for (int s = 0; s < KTILES; ++s) {
        const unsigned short* A = (s == 0) ? A0 : (s == 1) ? A1 : A2;
        #pragma unroll 1
        for (int q = 0; q < 4; ++q) {
            const int k0 = s * 128 + q * 32;     // k into Wt
            // stage A: 128 rows x 32 k bf16 = 512 x 16B, 2/thread
            #pragma unroll
            for (int f = 0; f < 2; ++f) {
                int fid = tid + f * 256;
                int r = fid >> 2, c8 = fid & 3;
                int row = rowbase + r;
                uint4 v = make_uint4(0u, 0u, 0u, 0u);
                if (row < M) v = *(const uint4*)&A[(size_t)row * DD + q * 32 + c8 * 8];
                *(uint4*)&As[r][c8 * 8] = v;
            }
            // stage B: Bs[n][0..32) = Wt[n][k0..k0+32) (512 x 16B, 2/thread)
            #pragma unroll
            for (int f = 0; f < 2; ++f) {
                int fid = tid + f * 256;
                int n = fid >> 2, sg = fid & 3;
                *(uint4*)&Bs[n][sg * 8] = *(const uint4*)&Wt[(size_t)n * K + k0 + sg * 8];
            }
            __syncthreads();
            bf16x8 af[2];
            #pragma unroll
            for (int mf = 0; mf < 2; ++mf)
                af[mf] = *(const bf16x8*)&As[w * 32 + mf * 16 + m16][kg * 8];
            #pragma unroll
            for (int nf = 0; nf < 8; ++nf) {
                bf16x8 bfr = *(const bf16x8*)&Bs[nf * 16 + m16][kg * 8];
                #pragma unroll
                for (int mf = 0; mf < 2; ++mf)
                    acc[mf][nf] = __builtin_amdgcn_mfma_f32_16x16x32_bf16(af[mf], bfr, acc[mf][nf], 0, 0, 0);
            }
            __syncthreads();
        }
    }
    // epilogue: bias + leaky-relu, bf16 store
    #pragma unroll
    for (int mf = 0; mf < 2; ++mf) {
        #pragma unroll
        for (int nf = 0; nf < 8; ++nf) {
            int col = nf * 16 + m16;
            float bv = bias[col];
            #pragma unroll
            for (int r = 0; r < 4; ++r) {
                int row = rowbase + w * 32 + mf * 16 + kg * 4 + r;
                if (row < M) {
                    float v = acc[mf][nf][r] + bv;
                    v = (v > 0.f) ? v : 0.01f * v;
                    out[(size_t)row * 128 + col] = f2bf(v);
                }
            }
        }
    }
}

// ---------------------------------------------------------------------------
// Head over bf16 hidden: out[i,h] = sum_c x[i,c]*Wh[h,c] + bh[h]; wave per row
// ---------------------------------------------------------------------------
__global__ __launch_bounds__(256)
void head_kernel(const unsigned short* __restrict__ x, const float* __restrict__ Wh,
                 const float* __restrict__ bh, float* __restrict__ out, int M) {
    __shared__ float w[8][128];
    int tid = threadIdx.x;
    for (int i = tid; i < 1024; i += 256) w[i >> 7][i & 127] = Wh[i];
    __syncthreads();
    int row = blockIdx.x * 4 + (tid >> 6);
    if (row >= M) return;
    int lane = tid & 63;
    unsigned int v = *(const unsigned int*)&x[(size_t)row * DD + lane * 2];
    float vx = bf2f(v & 0xFFFFu), vy = bf2f(v >> 16);
    float acc[8];
    #pragma unroll
    for (int h = 0; h < 8; ++h)
        acc[h] = vx * w[h][lane * 2] + vy * w[h][lane * 2 + 1];
    #pragma unroll
    for (int h = 0; h < 8; ++h) {
        float s = acc[h];
        #pragma unroll
        for (int d = 32; d >= 1; d >>= 1) s += __shfl_xor(s, d);
        acc[h] = s;
    }
    if (lane == 0) {
        #pragma unroll
        for (int h = 0; h < 8; ++h) out[(size_t)row * 8 + h] = acc[h] + bh[h];
    }
}

// ---------------------------------------------------------------------------
extern "C" void kernel_launch(void* const* d_in, const int* in_sizes, int n_in,
                              void* d_out, int out_size, void* d_ws, size_t ws_size,
                              hipStream_t stream) {
    const float* x_b = (const float*)d_in[0];
    const float* x_s = (const float*)d_in[1];
    const float* Wl  = (const float*)d_in[2];
    const float* bl  = (const float*)d_in[3];
    const float* Wr  = (const float*)d_in[4];
    const float* Wh  = (const float*)d_in[5];
    const float* bh  = (const float*)d_in[6];
    const int* ei_bb = (const int*)d_in[7];
    const int* ei_sb = (const int*)d_in[8];
    const int* ei_bs = (const int*)d_in[9];
    float* out = (float*)d_out;

    char* p = (char*)d_ws;
    auto alloc = [&](size_t bytes) { char* r = p; p += (bytes + 255) & ~255ull; return r; };
    int* off_bb = (int*)alloc((NB + 1) * 4);
    int* off_sb = (int*)alloc((NB + 1) * 4);
    int* off_bs = (int*)alloc((NS + 1) * 4);
    int* csr_bb = (int*)alloc((size_t)E_BB * 4);
    int* csr_sb = (int*)alloc((size_t)E_SB * 4);
    int* csr_bs = (int*)alloc((size_t)E_BS * 4);
    int* tick   = (int*)alloc((size_t)NB * 4);
    int* bsum   = (int*)alloc(1024 * 4);
    unsigned short* xb16 = (unsigned short*)alloc((size_t)NB * 128 * 2);
    unsigned short* xs16 = (unsigned short*)alloc((size_t)NS * 128 * 2);
    unsigned short* m1  = (unsigned short*)alloc((size_t)NB * 128 * 2);
    unsigned short* m2  = (unsigned short*)alloc((size_t)NB * 128 * 2);
    unsigned short* m3  = (unsigned short*)alloc((size_t)NS * 128 * 2);
    unsigned short* hb  = (unsigned short*)alloc((size_t)NB * 128 * 2);
    unsigned short* wt0 = (unsigned short*)alloc(128 * 384 * 2);
    unsigned short* wt1 = (unsigned short*)alloc(128 * 384 * 2);
    unsigned short* wts = (unsigned short*)alloc(128 * 256 * 2);
    float* bb0 = (float*)alloc(128 * 4);
    float* bb1 = (float*)alloc(128 * 4);
    float* bs0 = (float*)alloc(128 * 4);

    prep_weights<<<192, 256, 0, stream>>>(Wl, bl, Wr, wt0, wt1, wts, bb0, bb1, bs0);
    cvt_bf16<<<(NB * 128 / 4 + 255) / 256, 256, 0, stream>>>(x_b, xb16, NB * 128 / 4);
    cvt_bf16<<<(NS * 128 / 4 + 255) / 256, 256, 0, stream>>>(x_s, xs16, NS * 128 / 4);

    auto build_csr = [&](const int* ei, int E, int n, int* off, int* csr) {
        hipMemsetAsync(off, 0, (size_t)(n + 1) * 4, stream);
        hist_kernel<<<(E + 255) / 256, 256, 0, stream>>>(ei + E, E, off);
        int n1 = n + 1;
        int nb = (n1 + SCAN_B - 1) / SCAN_B;   // <=391 <=1024
        scan_blocksums<<<nb, SCAN_B, 0, stream>>>(off, n1, bsum);
        scan_bsum_exclusive<<<1, 1024, 0, stream>>>(bsum, nb);
        scan_apply<<<nb, SCAN_B, 0, stream>>>(off, n1, bsum);
        hipMemsetAsync(tick, 0, (size_t)n * 4, stream);
        fill_kernel<<<(E + 255) / 256, 256, 0, stream>>>(ei, ei + E, E, off, tick, csr);
    };
    build_csr(ei_bb, E_BB, NB, off_bb, csr_bb);
    build_csr(ei_sb, E_SB, NB, off_sb, csr_sb);
    build_csr(ei_bs, E_BS, NS, off_bs, csr_bs);

    // ---- layer 0 ----
    agg_mean_bf16<<<(NB + 3) / 4, 256, 0, stream>>>(xb16, off_bb, csr_bb, m1, NB);
    agg_mean_bf16<<<(NB + 3) / 4, 256, 0, stream>>>(xs16, off_sb, csr_sb, m2, NB);
    agg_mean_bf16<<<(NS + 3) / 4, 256, 0, stream>>>(xb16, off_bs, csr_bs, m3, NS);
    gemm_mfma<3><<<(NB + 127) / 128, 256, 0, stream>>>(m1, m2, xb16, wt0, bb0, hb, NB);
    gemm_mfma<2><<<(NS + 127) / 128, 256, 0, stream>>>(m3, xs16, nullptr, wts, bs0, m3, NS); // in-place -> h_s

    // ---- layer 1 (seller update is dead code: output only needs x_b) ----
    agg_mean_bf16<<<(NB + 3) / 4, 256, 0, stream>>>(hb, off_bb, csr_bb, m1, NB);
    agg_mean_bf16<<<(NB + 3) / 4, 256, 0, stream>>>(m3, off_sb, csr_sb, m2, NB);
    gemm_mfma<3><<<(NB + 127) / 128, 256, 0, stream>>>(m1, m2, hb, wt1, bb1, m1, NB); // in-place

    // ---- heads ----
    head_kernel<<<(NB + 3) / 4, 256, 0, stream>>>(m1, Wh, bh, out, NB);
}

// Round 12
// 629.753 us; speedup vs baseline: 70.6169x; 1.2579x over previous
//
#include <hip/hip_runtime.h>

// Problem constants (match reference)
#define NB 100000
#define NS 50000
#define DD 128
constexpr int E_BB = 800000, E_SB = 400000, E_BS = 400000;

typedef __attribute__((ext_vector_type(8))) short bf16x8;
typedef __attribute__((ext_vector_type(4))) float f32x4;

__device__ inline unsigned short f2bf(float f) {    // fp32 -> bf16 RNE
    unsigned int u = __float_as_uint(f);
    u += 0x7FFF + ((u >> 16) & 1);
    return (unsigned short)(u >> 16);
}
__device__ inline float bf2f(unsigned int lo16) {   // bf16 (low 16 bits) -> fp32
    return __uint_as_float(lo16 << 16);
}

// ---------------------------------------------------------------------------
// fp32 -> bf16 feature conversion (R9-R11 verified: halves gather bytes, absmax ok)
// ---------------------------------------------------------------------------
__global__ __launch_bounds__(256)
void cvt_bf16(const float* __restrict__ in, unsigned short* __restrict__ out, int n4) {
    int i = blockIdx.x * blockDim.x + threadIdx.x;
    if (i < n4) {
        float4 v = *(const float4*)&in[i * 4];
        ushort4 s;
        s.x = f2bf(v.x); s.y = f2bf(v.y); s.z = f2bf(v.z); s.w = f2bf(v.w);
        *(ushort4*)&out[i * 4] = s;
    }
}

// ---------------------------------------------------------------------------
// Weight prep (bf16, transposed [n][k] for MFMA B staging)
// ---------------------------------------------------------------------------
__global__ void prep_weights(const float* __restrict__ Wl, const float* __restrict__ bl,
                             const float* __restrict__ Wr,
                             unsigned short* __restrict__ wt0, unsigned short* __restrict__ wt1,
                             unsigned short* __restrict__ wts,
                             float* __restrict__ bb0, float* __restrict__ bb1,
                             float* __restrict__ bs0) {
    int i = blockIdx.x * blockDim.x + threadIdx.x;
    if (i < 128 * 384) {
        int n = i / 384, k = i % 384;
        #pragma unroll
        for (int l = 0; l < 2; ++l) {
            float v;
            if (k < 128)      v = Wl[((l*3 + 0)*128 + k)*128 + n];
            else if (k < 256) v = Wl[((l*3 + 1)*128 + (k-128))*128 + n];
            else              v = Wr[((l*3 + 0)*128 + (k-256))*128 + n]
                                + Wr[((l*3 + 1)*128 + (k-256))*128 + n];
            (l ? wt1 : wt0)[i] = f2bf(v);
        }
    }
    if (i < 128 * 256) {
        int n = i / 256, k = i % 256;
        float v = (k < 128) ? Wl[((0*3 + 2)*128 + k)*128 + n]
                            : Wr[((0*3 + 2)*128 + (k-128))*128 + n];
        wts[i] = f2bf(v);
    }
    if (i < 128) {
        bb0[i] = bl[(0*3 + 0)*128 + i] + bl[(0*3 + 1)*128 + i];
        bb1[i] = bl[(1*3 + 0)*128 + i] + bl[(1*3 + 1)*128 + i];
        bs0[i] = bl[(0*3 + 2)*128 + i];
    }
}

// ---------------------------------------------------------------------------
// CSR build: histogram -> 3-pass hierarchical scan -> atomic-ticket fill
// (R4 evidence: single-block scan was 35% of total; fixed+verified R8)
// ---------------------------------------------------------------------------
__global__ void hist_kernel(const int* __restrict__ dst, int E, int* __restrict__ off) {
    int i = blockIdx.x * blockDim.x + threadIdx.x;
    if (i < E) {
        int d = dst[i];
        atomicAdd(&off[d + 1], 1);
    }
}

#define SCAN_B 256
__global__ __launch_bounds__(SCAN_B)
void scan_blocksums(const int* __restrict__ a, int n, int* __restrict__ bsum) {
    __shared__ int red[SCAN_B];
    int t = threadIdx.x;
    int i = blockIdx.x * SCAN_B + t;
    red[t] = (i < n) ? a[i] : 0;
    __syncthreads();
    #pragma unroll
    for (int d = SCAN_B / 2; d > 0; d >>= 1) {
        if (t < d) red[t] += red[t + d];
        __syncthreads();
    }
    if (t == 0) bsum[blockIdx.x] = red[0];
}

__global__ __launch_bounds__(1024)
void scan_bsum_exclusive(int* __restrict__ bsum, int nb) {
    __shared__ int s[1024];
    int t = threadIdx.x;
    s[t] = (t < nb) ? bsum[t] : 0;
    __syncthreads();
    for (int d = 1; d < 1024; d <<= 1) {
        int u = (t >= d) ? s[t - d] : 0;
        __syncthreads();
        s[t] += u;
        __syncthreads();
    }
    if (t < nb) bsum[t] = (t == 0) ? 0 : s[t - 1];
}

__global__ __launch_bounds__(SCAN_B)
void scan_apply(int* __restrict__ a, int n, const int* __restrict__ bsum) {
    __shared__ int s[SCAN_B];
    int t = threadIdx.x;
    int i = blockIdx.x * SCAN_B + t;
    int v = (i < n) ? a[i] : 0;
    s[t] = v;
    __syncthreads();
    #pragma unroll
    for (int d = 1; d < SCAN_B; d <<= 1) {
        int u = (t >= d) ? s[t - d] : 0;
        __syncthreads();
        s[t] += u;
        __syncthreads();
    }
    if (i < n) a[i] = s[t] + bsum[blockIdx.x];
}

__global__ void fill_kernel(const int* __restrict__ src, const int* __restrict__ dst, int E,
                            const int* __restrict__ off, int* __restrict__ tick,
                            int* __restrict__ csr) {
    int i = blockIdx.x * blockDim.x + threadIdx.x;
    if (i < E) {
        int d = dst[i];
        int pos = off[d] + atomicAdd(&tick[d], 1);
        csr[pos] = src[i];
    }
}

// ---------------------------------------------------------------------------
// Mean aggregation, MLP-optimized (R11): half-wave (32 lanes) per node with
// uint2 (4 bf16) per lane + 4x edge unroll -> up to 8 outstanding 256B gathers
// per wave (was 1). R11 evidence: 1-gather-deep version was latency-bound at
// 84us, 1.43TB/s effective, VALUBusy 21% (FETCH halved but time only -19%).
// Adds stay in sequential edge order (rounding identical to R11).
// ---------------------------------------------------------------------------
__global__ __launch_bounds__(256)
void agg_mean_bf16(const unsigned short* __restrict__ xsrc, const int* __restrict__ off,
                   const int* __restrict__ csr, unsigned short* __restrict__ out, int n) {
    int node = blockIdx.x * 8 + (threadIdx.x >> 5);
    if (node >= n) return;
    int lane = threadIdx.x & 31;
    int s = off[node], e = off[node + 1];
    float a0 = 0.f, a1 = 0.f, a2 = 0.f, a3 = 0.f;
    int p = s;
    for (; p + 4 <= e; p += 4) {
        int j0 = csr[p + 0], j1 = csr[p + 1], j2 = csr[p + 2], j3 = csr[p + 3];
        uint2 v0 = *(const uint2*)&xsrc[(size_t)j0 * DD + lane * 4];
        uint2 v1 = *(const uint2*)&xsrc[(size_t)j1 * DD + lane * 4];
        uint2 v2 = *(const uint2*)&xsrc[(size_t)j2 * DD + lane * 4];
        uint2 v3 = *(const uint2*)&xsrc[(size_t)j3 * DD + lane * 4];
        a0 += bf2f(v0.x & 0xFFFFu); a1 += bf2f(v0.x >> 16);
        a2 += bf2f(v0.y & 0xFFFFu); a3 += bf2f(v0.y >> 16);
        a0 += bf2f(v1.x & 0xFFFFu); a1 += bf2f(v1.x >> 16);
        a2 += bf2f(v1.y & 0xFFFFu); a3 += bf2f(v1.y >> 16);
        a0 += bf2f(v2.x & 0xFFFFu); a1 += bf2f(v2.x >> 16);
        a2 += bf2f(v2.y & 0xFFFFu); a3 += bf2f(v2.y >> 16);
        a0 += bf2f(v3.x & 0xFFFFu); a1 += bf2f(v3.x >> 16);
        a2 += bf2f(v3.y & 0xFFFFu); a3 += bf2f(v3.y >> 16);
    }
    for (; p < e; ++p) {
        int j = csr[p];
        uint2 v = *(const uint2*)&xsrc[(size_t)j * DD + lane * 4];
        a0 += bf2f(v.x & 0xFFFFu); a1 += bf2f(v.x >> 16);
        a2 += bf2f(v.y & 0xFFFFu); a3 += bf2f(v.y >> 16);
    }
    float inv = 1.0f / fmaxf((float)(e - s), 1.0f);
    uint2 r;
    r.x = ((unsigned int)f2bf(a1 * inv) << 16) | (unsigned int)f2bf(a0 * inv);
    r.y = ((unsigned int)f2bf(a3 * inv) << 16) | (unsigned int)f2bf(a2 * inv);
    *(uint2*)&out[(size_t)node * DD + lane * 4] = r;
}

// ---------------------------------------------------------------------------
// MFMA GEMM: out(bf16) = leakyrelu([A0|A1|A2](bf16)@W + bias).
// R8->R9 verified: MFMA moved gemms out of top-5; bf16 A halves A-fetch.
// BM=128, 4 waves x 32 rows, per-wave 2x8 frags of 16x16x32; fp32 accum.
// In-place-safe (block reads only its own 128 output rows; writes after k-loop).
// Layouts (m89-verified): A row=lane&15, k=(lane>>4)*8+j; B col=lane&15;
// D row=(lane>>4)*4+reg, col=lane&15.
// ---------------------------------------------------------------------------
template<int KTILES>
__global__ __launch_bounds__(256)
void gemm_mfma(const unsigned short* __restrict__ A0, const unsigned short* __restrict__ A1,
               const unsigned short* __restrict__ A2, const unsigned short* __restrict__ Wt,
               const float* __restrict__ bias, unsigned short* __restrict__ out, int M) {
    constexpr int K = KTILES * 128;
    __shared__ unsigned short As[128][32];   // [m][k] bf16, 8KB
    __shared__ unsigned short Bs[128][32];   // [n][k] bf16, 8KB
    const int tid = threadIdx.x;
    const int lane = tid & 63;
    const int w = tid >> 6;            // wave 0..3 -> rows w*32..+32
    const int rowbase = blockIdx.x * 128;
    const int m16 = lane & 15;
    const int kg  = lane >> 4;         // k-group 0..3

    f32x4 acc[2][8] = {};

    #pragma unroll 1
    for (int s = 0; s < KTILES; ++s) {
        const unsigned short* A = (s == 0) ? A0 : (s == 1) ? A1 : A2;
        #pragma unroll 1
        for (int q = 0; q < 4; ++q) {
            const int k0 = s * 128 + q * 32;     // k into Wt
            // stage A: 128 rows x 32 k bf16 = 512 x 16B, 2/thread
            #pragma unroll
            for (int f = 0; f < 2; ++f) {
                int fid = tid + f * 256;
                int r = fid >> 2, c8 = fid & 3;
                int row = rowbase + r;
                uint4 v = make_uint4(0u, 0u, 0u, 0u);
                if (row < M) v = *(const uint4*)&A[(size_t)row * DD + q * 32 + c8 * 8];
                *(uint4*)&As[r][c8 * 8] = v;
            }
            // stage B: Bs[n][0..32) = Wt[n][k0..k0+32) (512 x 16B, 2/thread)
            #pragma unroll
            for (int f = 0; f < 2; ++f) {
                int fid = tid + f * 256;
                int n = fid >> 2, sg = fid & 3;
                *(uint4*)&Bs[n][sg * 8] = *(const uint4*)&Wt[(size_t)n * K + k0 + sg * 8];
            }
            __syncthreads();
            bf16x8 af[2];
            #pragma unroll
            for (int mf = 0; mf < 2; ++mf)
                af[mf] = *(const bf16x8*)&As[w * 32 + mf * 16 + m16][kg * 8];
            #pragma unroll
            for (int nf = 0; nf < 8; ++nf) {
                bf16x8 bfr = *(const bf16x8*)&Bs[nf * 16 + m16][kg * 8];
                #pragma unroll
                for (int mf = 0; mf < 2; ++mf)
                    acc[mf][nf] = __builtin_amdgcn_mfma_f32_16x16x32_bf16(af[mf], bfr, acc[mf][nf], 0, 0, 0);
            }
            __syncthreads();
        }
    }
    // epilogue: bias + leaky-relu, bf16 store
    #pragma unroll
    for (int mf = 0; mf < 2; ++mf) {
        #pragma unroll
        for (int nf = 0; nf < 8; ++nf) {
            int col = nf * 16 + m16;
            float bv = bias[col];
            #pragma unroll
            for (int r = 0; r < 4; ++r) {
                int row = rowbase + w * 32 + mf * 16 + kg * 4 + r;
                if (row < M) {
                    float v = acc[mf][nf][r] + bv;
                    v = (v > 0.f) ? v : 0.01f * v;
                    out[(size_t)row * 128 + col] = f2bf(v);
                }
            }
        }
    }
}

// ---------------------------------------------------------------------------
// Head over bf16 hidden: out[i,h] = sum_c x[i,c]*Wh[h,c] + bh[h]; wave per row
// ---------------------------------------------------------------------------
__global__ __launch_bounds__(256)
void head_kernel(const unsigned short* __restrict__ x, const float* __restrict__ Wh,
                 const float* __restrict__ bh, float* __restrict__ out, int M) {
    __shared__ float w[8][128];
    int tid = threadIdx.x;
    for (int i = tid; i < 1024; i += 256) w[i >> 7][i & 127] = Wh[i];
    __syncthreads();
    int row = blockIdx.x * 4 + (tid >> 6);
    if (row >= M) return;
    int lane = tid & 63;
    unsigned int v = *(const unsigned int*)&x[(size_t)row * DD + lane * 2];
    float vx = bf2f(v & 0xFFFFu), vy = bf2f(v >> 16);
    float acc[8];
    #pragma unroll
    for (int h = 0; h < 8; ++h)
        acc[h] = vx * w[h][lane * 2] + vy * w[h][lane * 2 + 1];
    #pragma unroll
    for (int h = 0; h < 8; ++h) {
        float s = acc[h];
        #pragma unroll
        for (int d = 32; d >= 1; d >>= 1) s += __shfl_xor(s, d);
        acc[h] = s;
    }
    if (lane == 0) {
        #pragma unroll
        for (int h = 0; h < 8; ++h) out[(size_t)row * 8 + h] = acc[h] + bh[h];
    }
}

// ---------------------------------------------------------------------------
extern "C" void kernel_launch(void* const* d_in, const int* in_sizes, int n_in,
                              void* d_out, int out_size, void* d_ws, size_t ws_size,
                              hipStream_t stream) {
    const float* x_b = (const float*)d_in[0];
    const float* x_s = (const float*)d_in[1];
    const float* Wl  = (const float*)d_in[2];
    const float* bl  = (const float*)d_in[3];
    const float* Wr  = (const float*)d_in[4];
    const float* Wh  = (const float*)d_in[5];
    const float* bh  = (const float*)d_in[6];
    const int* ei_bb = (const int*)d_in[7];
    const int* ei_sb = (const int*)d_in[8];
    const int* ei_bs = (const int*)d_in[9];
    float* out = (float*)d_out;

    char* p = (char*)d_ws;
    auto alloc = [&](size_t bytes) { char* r = p; p += (bytes + 255) & ~255ull; return r; };
    int* off_bb = (int*)alloc((NB + 1) * 4);
    int* off_sb = (int*)alloc((NB + 1) * 4);
    int* off_bs = (int*)alloc((NS + 1) * 4);
    int* csr_bb = (int*)alloc((size_t)E_BB * 4);
    int* csr_sb = (int*)alloc((size_t)E_SB * 4);
    int* csr_bs = (int*)alloc((size_t)E_BS * 4);
    int* tick   = (int*)alloc((size_t)NB * 4);
    int* bsum   = (int*)alloc(1024 * 4);
    unsigned short* xb16 = (unsigned short*)alloc((size_t)NB * 128 * 2);
    unsigned short* xs16 = (unsigned short*)alloc((size_t)NS * 128 * 2);
    unsigned short* m1  = (unsigned short*)alloc((size_t)NB * 128 * 2);
    unsigned short* m2  = (unsigned short*)alloc((size_t)NB * 128 * 2);
    unsigned short* m3  = (unsigned short*)alloc((size_t)NS * 128 * 2);
    unsigned short* hb  = (unsigned short*)alloc((size_t)NB * 128 * 2);
    unsigned short* wt0 = (unsigned short*)alloc(128 * 384 * 2);
    unsigned short* wt1 = (unsigned short*)alloc(128 * 384 * 2);
    unsigned short* wts = (unsigned short*)alloc(128 * 256 * 2);
    float* bb0 = (float*)alloc(128 * 4);
    float* bb1 = (float*)alloc(128 * 4);
    float* bs0 = (float*)alloc(128 * 4);

    prep_weights<<<192, 256, 0, stream>>>(Wl, bl, Wr, wt0, wt1, wts, bb0, bb1, bs0);
    cvt_bf16<<<(NB * 128 / 4 + 255) / 256, 256, 0, stream>>>(x_b, xb16, NB * 128 / 4);
    cvt_bf16<<<(NS * 128 / 4 + 255) / 256, 256, 0, stream>>>(x_s, xs16, NS * 128 / 4);

    auto build_csr = [&](const int* ei, int E, int n, int* off, int* csr) {
        hipMemsetAsync(off, 0, (size_t)(n + 1) * 4, stream);
        hist_kernel<<<(E + 255) / 256, 256, 0, stream>>>(ei + E, E, off);
        int n1 = n + 1;
        int nb = (n1 + SCAN_B - 1) / SCAN_B;   // <=391 <=1024
        scan_blocksums<<<nb, SCAN_B, 0, stream>>>(off, n1, bsum);
        scan_bsum_exclusive<<<1, 1024, 0, stream>>>(bsum, nb);
        scan_apply<<<nb, SCAN_B, 0, stream>>>(off, n1, bsum);
        hipMemsetAsync(tick, 0, (size_t)n * 4, stream);
        fill_kernel<<<(E + 255) / 256, 256, 0, stream>>>(ei, ei + E, E, off, tick, csr);
    };
    build_csr(ei_bb, E_BB, NB, off_bb, csr_bb);
    build_csr(ei_sb, E_SB, NB, off_sb, csr_sb);
    build_csr(ei_bs, E_BS, NS, off_bs, csr_bs);

    // ---- layer 0 ----
    agg_mean_bf16<<<(NB + 7) / 8, 256, 0, stream>>>(xb16, off_bb, csr_bb, m1, NB);
    agg_mean_bf16<<<(NB + 7) / 8, 256, 0, stream>>>(xs16, off_sb, csr_sb, m2, NB);
    agg_mean_bf16<<<(NS + 7) / 8, 256, 0, stream>>>(xb16, off_bs, csr_bs, m3, NS);
    gemm_mfma<3><<<(NB + 127) / 128, 256, 0, stream>>>(m1, m2, xb16, wt0, bb0, hb, NB);
    gemm_mfma<2><<<(NS + 127) / 128, 256, 0, stream>>>(m3, xs16, nullptr, wts, bs0, m3, NS); // in-place -> h_s

    // ---- layer 1 (seller update is dead code: output only needs x_b) ----
    agg_mean_bf16<<<(NB + 7) / 8, 256, 0, stream>>>(hb, off_bb, csr_bb, m1, NB);
    agg_mean_bf16<<<(NB + 7) / 8, 256, 0, stream>>>(m3, off_sb, csr_sb, m2, NB);
    gemm_mfma<3><<<(NB + 127) / 128, 256, 0, stream>>>(m1, m2, hb, wt1, bb1, m1, NB); // in-place

    // ---- heads ----
    head_kernel<<<(NB + 3) / 4, 256, 0, stream>>>(m1, Wh, bh, out, NB);
}

// Round 13
// 584.981 us; speedup vs baseline: 76.0216x; 1.0765x over previous
//
#include <hip/hip_runtime.h>

// Problem constants (match reference)
#define NB 100000
#define NS 50000
#define DD 128
constexpr int E_BB = 800000, E_SB = 400000, E_BS = 400000;

typedef __attribute__((ext_vector_type(8))) short bf16x8;
typedef __attribute__((ext_vector_type(4))) float f32x4;

__device__ inline unsigned short f2bf(float f) {    // fp32 -> bf16 RNE
    unsigned int u = __float_as_uint(f);
    u += 0x7FFF + ((u >> 16) & 1);
    return (unsigned short)(u >> 16);
}
__device__ inline float bf2f(unsigned int lo16) {   // bf16 (low 16 bits) -> fp32
    return __uint_as_float(lo16 << 16);
}

// ---------------------------------------------------------------------------
// fp32 -> bf16 feature conversion (R9-R11 verified: halves gather bytes, absmax ok)
// ---------------------------------------------------------------------------
__global__ __launch_bounds__(256)
void cvt_bf16(const float* __restrict__ in, unsigned short* __restrict__ out, int n4) {
    int i = blockIdx.x * blockDim.x + threadIdx.x;
    if (i < n4) {
        float4 v = *(const float4*)&in[i * 4];
        ushort4 s;
        s.x = f2bf(v.x); s.y = f2bf(v.y); s.z = f2bf(v.z); s.w = f2bf(v.w);
        *(ushort4*)&out[i * 4] = s;
    }
}

// ---------------------------------------------------------------------------
// Weight prep (bf16, transposed [n][k] for MFMA B staging)
// ---------------------------------------------------------------------------
__global__ void prep_weights(const float* __restrict__ Wl, const float* __restrict__ bl,
                             const float* __restrict__ Wr,
                             unsigned short* __restrict__ wt0, unsigned short* __restrict__ wt1,
                             unsigned short* __restrict__ wts,
                             float* __restrict__ bb0, float* __restrict__ bb1,
                             float* __restrict__ bs0) {
    int i = blockIdx.x * blockDim.x + threadIdx.x;
    if (i < 128 * 384) {
        int n = i / 384, k = i % 384;
        #pragma unroll
        for (int l = 0; l < 2; ++l) {
            float v;
            if (k < 128)      v = Wl[((l*3 + 0)*128 + k)*128 + n];
            else if (k < 256) v = Wl[((l*3 + 1)*128 + (k-128))*128 + n];
            else              v = Wr[((l*3 + 0)*128 + (k-256))*128 + n]
                                + Wr[((l*3 + 1)*128 + (k-256))*128 + n];
            (l ? wt1 : wt0)[i] = f2bf(v);
        }
    }
    if (i < 128 * 256) {
        int n = i / 256, k = i % 256;
        float v = (k < 128) ? Wl[((0*3 + 2)*128 + k)*128 + n]
                            : Wr[((0*3 + 2)*128 + (k-128))*128 + n];
        wts[i] = f2bf(v);
    }
    if (i < 128) {
        bb0[i] = bl[(0*3 + 0)*128 + i] + bl[(0*3 + 1)*128 + i];
        bb1[i] = bl[(1*3 + 0)*128 + i] + bl[(1*3 + 1)*128 + i];
        bs0[i] = bl[(0*3 + 2)*128 + i];
    }
}

// ---------------------------------------------------------------------------
// CSR build: histogram -> 3-pass hierarchical scan -> atomic-ticket fill
// (R4 evidence: single-block scan was 35% of total; fixed+verified R8)
// ---------------------------------------------------------------------------
__global__ void hist_kernel(const int* __restrict__ dst, int E, int* __restrict__ off) {
    int i = blockIdx.x * blockDim.x + threadIdx.x;
    if (i < E) {
        int d = dst[i];
        atomicAdd(&off[d + 1], 1);
    }
}

#define SCAN_B 256
__global__ __launch_bounds__(SCAN_B)
void scan_blocksums(const int* __restrict__ a, int n, int* __restrict__ bsum) {
    __shared__ int red[SCAN_B];
    int t = threadIdx.x;
    int i = blockIdx.x * SCAN_B + t;
    red[t] = (i < n) ? a[i] : 0;
    __syncthreads();
    #pragma unroll
    for (int d = SCAN_B / 2; d > 0; d >>= 1) {
        if (t < d) red[t] += red[t + d];
        __syncthreads();
    }
    if (t == 0) bsum[blockIdx.x] = red[0];
}

__global__ __launch_bounds__(1024)
void scan_bsum_exclusive(int* __restrict__ bsum, int nb) {
    __shared__ int s[1024];
    int t = threadIdx.x;
    s[t] = (t < nb) ? bsum[t] : 0;
    __syncthreads();
    for (int d = 1; d < 1024; d <<= 1) {
        int u = (t >= d) ? s[t - d] : 0;
        __syncthreads();
        s[t] += u;
        __syncthreads();
    }
    if (t < nb) bsum[t] = (t == 0) ? 0 : s[t - 1];
}

__global__ __launch_bounds__(SCAN_B)
void scan_apply(int* __restrict__ a, int n, const int* __restrict__ bsum) {
    __shared__ int s[SCAN_B];
    int t = threadIdx.x;
    int i = blockIdx.x * SCAN_B + t;
    int v = (i < n) ? a[i] : 0;
    s[t] = v;
    __syncthreads();
    #pragma unroll
    for (int d = 1; d < SCAN_B; d <<= 1) {
        int u = (t >= d) ? s[t - d] : 0;
        __syncthreads();
        s[t] += u;
        __syncthreads();
    }
    if (i < n) a[i] = s[t] + bsum[blockIdx.x];
}

__global__ void fill_kernel(const int* __restrict__ src, const int* __restrict__ dst, int E,
                            const int* __restrict__ off, int* __restrict__ tick,
                            int* __restrict__ csr) {
    int i = blockIdx.x * blockDim.x + threadIdx.x;
    if (i < E) {
        int d = dst[i];
        int pos = off[d] + atomicAdd(&tick[d], 1);
        csr[pos] = src[i];
    }
}

// ---------------------------------------------------------------------------
// Mean aggregation, MLP-optimized (R11->R12 verified: 84us -> <64us, out of
// top-5): half-wave (32 lanes) per node, uint2 per lane + 4x edge unroll ->
// up to 8 outstanding 256B gathers per wave.
// ---------------------------------------------------------------------------
__global__ __launch_bounds__(256)
void agg_mean_bf16(const unsigned short* __restrict__ xsrc, const int* __restrict__ off,
                   const int* __restrict__ csr, unsigned short* __restrict__ out, int n) {
    int node = blockIdx.x * 8 + (threadIdx.x >> 5);
    if (node >= n) return;
    int lane = threadIdx.x & 31;
    int s = off[node], e = off[node + 1];
    float a0 = 0.f, a1 = 0.f, a2 = 0.f, a3 = 0.f;
    int p = s;
    for (; p + 4 <= e; p += 4) {
        int j0 = csr[p + 0], j1 = csr[p + 1], j2 = csr[p + 2], j3 = csr[p + 3];
        uint2 v0 = *(const uint2*)&xsrc[(size_t)j0 * DD + lane * 4];
        uint2 v1 = *(const uint2*)&xsrc[(size_t)j1 * DD + lane * 4];
        uint2 v2 = *(const uint2*)&xsrc[(size_t)j2 * DD + lane * 4];
        uint2 v3 = *(const uint2*)&xsrc[(size_t)j3 * DD + lane * 4];
        a0 += bf2f(v0.x & 0xFFFFu); a1 += bf2f(v0.x >> 16);
        a2 += bf2f(v0.y & 0xFFFFu); a3 += bf2f(v0.y >> 16);
        a0 += bf2f(v1.x & 0xFFFFu); a1 += bf2f(v1.x >> 16);
        a2 += bf2f(v1.y & 0xFFFFu); a3 += bf2f(v1.y >> 16);
        a0 += bf2f(v2.x & 0xFFFFu); a1 += bf2f(v2.x >> 16);
        a2 += bf2f(v2.y & 0xFFFFu); a3 += bf2f(v2.y >> 16);
        a0 += bf2f(v3.x & 0xFFFFu); a1 += bf2f(v3.x >> 16);
        a2 += bf2f(v3.y & 0xFFFFu); a3 += bf2f(v3.y >> 16);
    }
    for (; p < e; ++p) {
        int j = csr[p];
        uint2 v = *(const uint2*)&xsrc[(size_t)j * DD + lane * 4];
        a0 += bf2f(v.x & 0xFFFFu); a1 += bf2f(v.x >> 16);
        a2 += bf2f(v.y & 0xFFFFu); a3 += bf2f(v.y >> 16);
    }
    float inv = 1.0f / fmaxf((float)(e - s), 1.0f);
    uint2 r;
    r.x = ((unsigned int)f2bf(a1 * inv) << 16) | (unsigned int)f2bf(a0 * inv);
    r.y = ((unsigned int)f2bf(a3 * inv) << 16) | (unsigned int)f2bf(a2 * inv);
    *(uint2*)&out[(size_t)node * DD + lane * 4] = r;
}

// ---------------------------------------------------------------------------
// MFMA GEMM: out(bf16) = leakyrelu([A0|A1|A2](bf16)@W + bias).
// R8->R9 verified: MFMA moved gemms out of top-5; bf16 A halves A-fetch.
// BM=128, 4 waves x 32 rows, per-wave 2x8 frags of 16x16x32; fp32 accum.
// In-place-safe (block reads only its own 128 output rows; writes after k-loop).
// Layouts (m89-verified): A row=lane&15, k=(lane>>4)*8+j; B col=lane&15;
// D row=(lane>>4)*4+reg, col=lane&15.
// ---------------------------------------------------------------------------
template<int KTILES>
__global__ __launch_bounds__(256)
void gemm_mfma(const unsigned short* __restrict__ A0, const unsigned short* __restrict__ A1,
               const unsigned short* __restrict__ A2, const unsigned short* __restrict__ Wt,
               const float* __restrict__ bias, unsigned short* __restrict__ out, int M) {
    constexpr int K = KTILES * 128;
    __shared__ unsigned short As[128][32];   // [m][k] bf16, 8KB
    __shared__ unsigned short Bs[128][32];   // [n][k] bf16, 8KB
    const int tid = threadIdx.x;
    const int lane = tid & 63;
    const int w = tid >> 6;            // wave 0..3 -> rows w*32..+32
    const int rowbase = blockIdx.x * 128;
    const int m16 = lane & 15;
    const int kg  = lane >> 4;         // k-group 0..3

    f32x4 acc[2][8] = {};

    #pragma unroll 1
    for (int s = 0; s < KTILES; ++s) {
        const unsigned short* A = (s == 0) ? A0 : (s == 1) ? A1 : A2;
        #pragma unroll 1
        for (int q = 0; q < 4; ++q) {
            const int k0 = s * 128 + q * 32;     // k into Wt
            // stage A: 128 rows x 32 k bf16 = 512 x 16B, 2/thread
            #pragma unroll
            for (int f = 0; f < 2; ++f) {
                int fid = tid + f * 256;
                int r = fid >> 2, c8 = fid & 3;
                int row = rowbase + r;
                uint4 v = make_uint4(0u, 0u, 0u, 0u);
                if (row < M) v = *(const uint4*)&A[(size_t)row * DD + q * 32 + c8 * 8];
                *(uint4*)&As[r][c8 * 8] = v;
            }
            // stage B: Bs[n][0..32) = Wt[n][k0..k0+32) (512 x 16B, 2/thread)
            #pragma unroll
            for (int f = 0; f < 2; ++f) {
                int fid = tid + f * 256;
                int n = fid >> 2, sg = fid & 3;
                *(uint4*)&Bs[n][sg * 8] = *(const uint4*)&Wt[(size_t)n * K + k0 + sg * 8];
            }
            __syncthreads();
            bf16x8 af[2];
            #pragma unroll
            for (int mf = 0; mf < 2; ++mf)
                af[mf] = *(const bf16x8*)&As[w * 32 + mf * 16 + m16][kg * 8];
            #pragma unroll
            for (int nf = 0; nf < 8; ++nf) {
                bf16x8 bfr = *(const bf16x8*)&Bs[nf * 16 + m16][kg * 8];
                #pragma unroll
                for (int mf = 0; mf < 2; ++mf)
                    acc[mf][nf] = __builtin_amdgcn_mfma_f32_16x16x32_bf16(af[mf], bfr, acc[mf][nf], 0, 0, 0);
            }
            __syncthreads();
        }
    }
    // epilogue: bias + leaky-relu, bf16 store
    #pragma unroll
    for (int mf = 0; mf < 2; ++mf) {
        #pragma unroll
        for (int nf = 0; nf < 8; ++nf) {
            int col = nf * 16 + m16;
            float bv = bias[col];
            #pragma unroll
            for (int r = 0; r < 4; ++r) {
                int row = rowbase + w * 32 + mf * 16 + kg * 4 + r;
                if (row < M) {
                    float v = acc[mf][nf][r] + bv;
                    v = (v > 0.f) ? v : 0.01f * v;
                    out[(size_t)row * 128 + col] = f2bf(v);
                }
            }
        }
    }
}

// ---------------------------------------------------------------------------
// Head (R12 rewrite): 16-lane group per row, grid-stride, weights in registers.
// R12 evidence: old wave-per-row head = 64us (top dispatch!) at 3% HBM,
// 48 serial shfl steps per row, 2/128 channels per lane. New: lane g owns
// channels g*8..+8 (uint4 = one coalesced 256B segment per row), 64 FMA +
// 4-step xor-tree over 16 lanes; Wh regs loaded once per thread (~12 rows).
// ---------------------------------------------------------------------------
__global__ __launch_bounds__(256)
void head_kernel(const unsigned short* __restrict__ x, const float* __restrict__ Wh,
                 const float* __restrict__ bh, float* __restrict__ out, int M) {
    const int tid = threadIdx.x;
    const int g = tid & 15;                              // lane in 16-group
    const int group = (blockIdx.x * 256 + tid) >> 4;     // global group id
    const int ngroups = (gridDim.x * 256) >> 4;
    // per-lane head weights: wreg[h][c] = Wh[h][g*8+c]
    float wreg[8][8];
    #pragma unroll
    for (int h = 0; h < 8; ++h) {
        float4 wa = *(const float4*)&Wh[h * 128 + g * 8];
        float4 wb = *(const float4*)&Wh[h * 128 + g * 8 + 4];
        wreg[h][0] = wa.x; wreg[h][1] = wa.y; wreg[h][2] = wa.z; wreg[h][3] = wa.w;
        wreg[h][4] = wb.x; wreg[h][5] = wb.y; wreg[h][6] = wb.z; wreg[h][7] = wb.w;
    }
    float bias[8];
    #pragma unroll
    for (int h = 0; h < 8; ++h) bias[h] = bh[h];

    for (int row = group; row < M; row += ngroups) {
        uint4 v = *(const uint4*)&x[(size_t)row * DD + g * 8];
        float xv[8];
        xv[0] = bf2f(v.x & 0xFFFFu); xv[1] = bf2f(v.x >> 16);
        xv[2] = bf2f(v.y & 0xFFFFu); xv[3] = bf2f(v.y >> 16);
        xv[4] = bf2f(v.z & 0xFFFFu); xv[5] = bf2f(v.z >> 16);
        xv[6] = bf2f(v.w & 0xFFFFu); xv[7] = bf2f(v.w >> 16);
        float acc[8];
        #pragma unroll
        for (int h = 0; h < 8; ++h) {
            float s = 0.f;
            #pragma unroll
            for (int c = 0; c < 8; ++c) s += xv[c] * wreg[h][c];
            acc[h] = s;
        }
        #pragma unroll
        for (int h = 0; h < 8; ++h) {
            #pragma unroll
            for (int d = 1; d < 16; d <<= 1) acc[h] += __shfl_xor(acc[h], d);
        }
        if (g == 0) {
            float4 o0 = make_float4(acc[0] + bias[0], acc[1] + bias[1],
                                    acc[2] + bias[2], acc[3] + bias[3]);
            float4 o1 = make_float4(acc[4] + bias[4], acc[5] + bias[5],
                                    acc[6] + bias[6], acc[7] + bias[7]);
            *(float4*)&out[(size_t)row * 8]     = o0;
            *(float4*)&out[(size_t)row * 8 + 4] = o1;
        }
    }
}

// ---------------------------------------------------------------------------
extern "C" void kernel_launch(void* const* d_in, const int* in_sizes, int n_in,
                              void* d_out, int out_size, void* d_ws, size_t ws_size,
                              hipStream_t stream) {
    const float* x_b = (const float*)d_in[0];
    const float* x_s = (const float*)d_in[1];
    const float* Wl  = (const float*)d_in[2];
    const float* bl  = (const float*)d_in[3];
    const float* Wr  = (const float*)d_in[4];
    const float* Wh  = (const float*)d_in[5];
    const float* bh  = (const float*)d_in[6];
    const int* ei_bb = (const int*)d_in[7];
    const int* ei_sb = (const int*)d_in[8];
    const int* ei_bs = (const int*)d_in[9];
    float* out = (float*)d_out;

    char* p = (char*)d_ws;
    auto alloc = [&](size_t bytes) { char* r = p; p += (bytes + 255) & ~255ull; return r; };
    int* off_bb = (int*)alloc((NB + 1) * 4);
    int* off_sb = (int*)alloc((NB + 1) * 4);
    int* off_bs = (int*)alloc((NS + 1) * 4);
    int* csr_bb = (int*)alloc((size_t)E_BB * 4);
    int* csr_sb = (int*)alloc((size_t)E_SB * 4);
    int* csr_bs = (int*)alloc((size_t)E_BS * 4);
    int* tick   = (int*)alloc((size_t)NB * 4);
    int* bsum   = (int*)alloc(1024 * 4);
    unsigned short* xb16 = (unsigned short*)alloc((size_t)NB * 128 * 2);
    unsigned short* xs16 = (unsigned short*)alloc((size_t)NS * 128 * 2);
    unsigned short* m1  = (unsigned short*)alloc((size_t)NB * 128 * 2);
    unsigned short* m2  = (unsigned short*)alloc((size_t)NB * 128 * 2);
    unsigned short* m3  = (unsigned short*)alloc((size_t)NS * 128 * 2);
    unsigned short* hb  = (unsigned short*)alloc((size_t)NB * 128 * 2);
    unsigned short* wt0 = (unsigned short*)alloc(128 * 384 * 2);
    unsigned short* wt1 = (unsigned short*)alloc(128 * 384 * 2);
    unsigned short* wts = (unsigned short*)alloc(128 * 256 * 2);
    float* bb0 = (float*)alloc(128 * 4);
    float* bb1 = (float*)alloc(128 * 4);
    float* bs0 = (float*)alloc(128 * 4);

    prep_weights<<<192, 256, 0, stream>>>(Wl, bl, Wr, wt0, wt1, wts, bb0, bb1, bs0);
    cvt_bf16<<<(NB * 128 / 4 + 255) / 256, 256, 0, stream>>>(x_b, xb16, NB * 128 / 4);
    cvt_bf16<<<(NS * 128 / 4 + 255) / 256, 256, 0, stream>>>(x_s, xs16, NS * 128 / 4);

    auto build_csr = [&](const int* ei, int E, int n, int* off, int* csr) {
        hipMemsetAsync(off, 0, (size_t)(n + 1) * 4, stream);
        hist_kernel<<<(E + 255) / 256, 256, 0, stream>>>(ei + E, E, off);
        int n1 = n + 1;
        int nb = (n1 + SCAN_B - 1) / SCAN_B;   // <=391 <=1024
        scan_blocksums<<<nb, SCAN_B, 0, stream>>>(off, n1, bsum);
        scan_bsum_exclusive<<<1, 1024, 0, stream>>>(bsum, nb);
        scan_apply<<<nb, SCAN_B, 0, stream>>>(off, n1, bsum);
        hipMemsetAsync(tick, 0, (size_t)n * 4, stream);
        fill_kernel<<<(E + 255) / 256, 256, 0, stream>>>(ei, ei + E, E, off, tick, csr);
    };
    build_csr(ei_bb, E_BB, NB, off_bb, csr_bb);
    build_csr(ei_sb, E_SB, NB, off_sb, csr_sb);
    build_csr(ei_bs, E_BS, NS, off_bs, csr_bs);

    // ---- layer 0 ----
    agg_mean_bf16<<<(NB + 7) / 8, 256, 0, stream>>>(xb16, off_bb, csr_bb, m1, NB);
    agg_mean_bf16<<<(NB + 7) / 8, 256, 0, stream>>>(xs16, off_sb, csr_sb, m2, NB);
    agg_mean_bf16<<<(NS + 7) / 8, 256, 0, stream>>>(xb16, off_bs, csr_bs, m3, NS);
    gemm_mfma<3><<<(NB + 127) / 128, 256, 0, stream>>>(m1, m2, xb16, wt0, bb0, hb, NB);
    gemm_mfma<2><<<(NS + 127) / 128, 256, 0, stream>>>(m3, xs16, nullptr, wts, bs0, m3, NS); // in-place -> h_s

    // ---- layer 1 (seller update is dead code: output only needs x_b) ----
    agg_mean_bf16<<<(NB + 7) / 8, 256, 0, stream>>>(hb, off_bb, csr_bb, m1, NB);
    agg_mean_bf16<<<(NB + 7) / 8, 256, 0, stream>>>(m3, off_sb, csr_sb, m2, NB);
    gemm_mfma<3><<<(NB + 127) / 128, 256, 0, stream>>>(m1, m2, hb, wt1, bb1, m1, NB); // in-place

    // ---- heads ----
    head_kernel<<<512, 256, 0, stream>>>(m1, Wh, bh, out, NB);
}